// Round 13
// baseline (352.592 us; speedup 1.0000x reference)
//
#include <hip/hip_runtime.h>

typedef unsigned short u16;
typedef __attribute__((ext_vector_type(4))) float f32x4;
typedef __attribute__((ext_vector_type(8))) short s16x8;

#define TOK 8192
#define NDIM 768
#define NHEADS 12
#define WHN 192            // window-heads
#define WHSZ 32768         // 512*64 elements per window-head plane
#define L2E 1.4426950408889634f
#define SCL2 (0.125f * L2E)

#if __has_builtin(__builtin_amdgcn_exp2f)
#define EXP2F __builtin_amdgcn_exp2f
#else
#define EXP2F exp2f
#endif

__device__ __forceinline__ u16 f2bf(float f) {
  union { float f; unsigned u; } x; x.f = f;
  unsigned r = x.u + 0x7fffu + ((x.u >> 16) & 1u);
  return (u16)(r >> 16);
}
__device__ __forceinline__ float bf2f(u16 u) {
  union { unsigned u; float f; } x; x.u = ((unsigned)u) << 16;
  return x.f;
}
// fast erf-based exact GELU (A&S 7.1.26, |err| <= 1.5e-7)
__device__ __forceinline__ float gelu_f(float v) {
  float z = fabsf(v) * 0.70710678118654752f;
  float t = __builtin_amdgcn_rcpf(1.0f + 0.3275911f * z);
  float poly = t * (0.254829592f +
               t * (-0.284496736f +
               t * (1.421413741f +
               t * (-1.453152027f + t * 1.061405429f))));
  float erfv = 1.0f - poly * __expf(-z * z);
  erfv = copysignf(erfv, v);
  return 0.5f * v * (1.0f + erfv);
}
__device__ __forceinline__ f32x4 mfma16(s16x8 a, s16x8 b, f32x4 c) {
  return __builtin_amdgcn_mfma_f32_16x16x32_bf16(a, b, c, 0, 0, 0);
}
__device__ __forceinline__ void glds16(const u16* g, u16* l) {
  __builtin_amdgcn_global_load_lds(
      (const __attribute__((address_space(1))) unsigned int*)g,
      (__attribute__((address_space(3))) unsigned int*)l, 16, 0, 0);
}
// counted vmcnt wait (literal immediates), with scheduling fence (rule #18)
template<int N> __device__ __forceinline__ void waitvm() {
  if constexpr (N == 0)      asm volatile("s_waitcnt vmcnt(0)" ::: "memory");
  else if constexpr (N == 2) asm volatile("s_waitcnt vmcnt(2)" ::: "memory");
  else if constexpr (N == 3) asm volatile("s_waitcnt vmcnt(3)" ::: "memory");
  else if constexpr (N == 4) asm volatile("s_waitcnt vmcnt(4)" ::: "memory");
  else if constexpr (N == 5) asm volatile("s_waitcnt vmcnt(5)" ::: "memory");
  else if constexpr (N == 6) asm volatile("s_waitcnt vmcnt(6)" ::: "memory");
  else if constexpr (N == 8) asm volatile("s_waitcnt vmcnt(8)" ::: "memory");
  __builtin_amdgcn_sched_barrier(0);
}
// window (wi in [0,16), n in [0,512)) -> flat spatial token index
__device__ __forceinline__ int tok_of(int wi, int n) {
  int b = wi >> 3;
  int d = (((wi >> 2) & 1) << 3) | (n >> 6);
  int h = (((wi >> 1) & 1) << 3) | ((n >> 3) & 7);
  int w = ((wi & 1) << 3) | (n & 7);
  return (b << 12) | (d << 8) | (h << 4) | w;
}

// ------ fp32 -> bf16 conversion (weights + rel-pos tables), optional scale ------
struct WConv {
  const float* src[11];
  u16* dst[11];
  int n[11];
  float scl[11];
};
__global__ __launch_bounds__(256) void conv_weights(WConv a) {
  int stride = gridDim.x * blockDim.x;
  int t0 = blockIdx.x * blockDim.x + threadIdx.x;
  for (int s = 0; s < 11; s++) {
    const float4* src = (const float4*)a.src[s];
    u16* dst = a.dst[s];
    float sc = a.scl[s];
    int n4 = a.n[s] >> 2;
    for (int i = t0; i < n4; i += stride) {
      float4 v = src[i];
      ushort4 o;
      o.x = f2bf(v.x * sc); o.y = f2bf(v.y * sc);
      o.z = f2bf(v.z * sc); o.w = f2bf(v.w * sc);
      *(ushort4*)(dst + 4 * (size_t)i) = o;
    }
  }
}

// ---------------- LayerNorm (fp32 in -> bf16 out) ----------------
__global__ __launch_bounds__(256) void ln_bf16(const float* __restrict__ in,
    const float* __restrict__ gamma, const float* __restrict__ beta,
    u16* __restrict__ out) {
  const int row = blockIdx.x;
  const int tid = threadIdx.x;
  const float* xr = in + (size_t)row * NDIM;
  float v0 = xr[tid], v1 = xr[tid + 256], v2 = xr[tid + 512];
  float s = v0 + v1 + v2;
  float q = v0 * v0 + v1 * v1 + v2 * v2;
  for (int o = 32; o; o >>= 1) { s += __shfl_down(s, o); q += __shfl_down(q, o); }
  __shared__ float ss[4], sq[4];
  int wave = tid >> 6, lane = tid & 63;
  if (lane == 0) { ss[wave] = s; sq[wave] = q; }
  __syncthreads();
  s = ss[0] + ss[1] + ss[2] + ss[3];
  q = sq[0] + sq[1] + sq[2] + sq[3];
  float mean = s * (1.0f / 768.0f);
  float var = q * (1.0f / 768.0f) - mean * mean;
  float rstd = rsqrtf(var + 1e-5f);
  u16* orow = out + (size_t)row * NDIM;
  float v[3] = {v0, v1, v2};
  #pragma unroll
  for (int i = 0; i < 3; i++) {
    int c = tid + i * 256;
    orow[c] = f2bf((v[i] - mean) * rstd * gamma[c] + beta[c]);
  }
}

// ---- GEMM: C[M,N] = A[M,K](bf16) * W[N,K]^T(bf16) + bias ----
// NBUF-buffer rotation, counted vmcnt, 1 raw barrier per K-step.
// Wave grid: TPB=256 -> 2x2 (wave tile WMxWN = BM/2 x BN/2);
//            TPB=512 -> 4x2 (wave tile BM/4 x BN/2) for high FLOP/LDS-byte.
// LDS swizzle (verified conflict-free): store source unit (L&3)^((L>>3)&3)
// at slot L&3; read g^((r>>1)&3). 2 lanes/bank = free.
// EPI 0: bf16 store; 2: gelu->bf16; 3: of=add1+bf2f(obf)+v (bf16 residual);
// EPI 6: packed QKV; EPI 7: dual-K fused (mlp2+ma2)
template<int BM, int BN, int TPB, int NBUF, int EPI>
__global__ __launch_bounds__(TPB) void gemm_bf16(
    const u16* __restrict__ A, const u16* __restrict__ W,
    const float* __restrict__ bias, int M, int N, int K,
    u16* __restrict__ obf, float* __restrict__ of,
    const float* __restrict__ add1,
    const u16* __restrict__ A2, const u16* __restrict__ W2, int K2,
    const float* __restrict__ bias2) {
  constexpr int BK = 32;
  constexpr int WROWS = (TPB == 512) ? 4 : 2;
  constexpr int WCOLS = TPB / 64 / WROWS;   // 2
  constexpr int WM = BM / WROWS, WN = BN / WCOLS;
  constexpr int MF = WM / 16, NF = WN / 16;
  constexpr int ACH = BM * BK / (8 * TPB);  // 16B chunks per thread for A
  constexpr int BCH = BN * BK / (8 * TPB);
  constexpr int LPT = ACH + BCH;            // glds per thread per tile
  __shared__ __align__(16) u16 As[NBUF][BM * BK];
  __shared__ __align__(16) u16 Bs[NBUF][BN * BK];
  const int bm = blockIdx.x, bn = blockIdx.y;
  const int tid = threadIdx.x;
  const int wave = tid >> 6, lane = tid & 63;
  const int wr = wave / WCOLS, wc = wave % WCOLS;
  const int g = lane >> 4, c15 = lane & 15;
  f32x4 acc[MF][NF] = {};
  // stage: linear LDS dest, 8-phase XOR-swizzled global source
  auto stage = [&](const u16* Ab_, const u16* Wb_, int Kst, int k0, int b) {
    #pragma unroll
    for (int i = 0; i < ACH; i++) {
      int L = i * TPB + tid;  // row = L>>2, unit = L&3, swz = u ^ ((row>>1)&3)
      glds16(Ab_ + (size_t)(L >> 2) * Kst + k0 + (((L & 3) ^ ((L >> 3) & 3)) * 8),
             &As[b][L * 8]);
    }
    #pragma unroll
    for (int i = 0; i < BCH; i++) {
      int L = i * TPB + tid;
      glds16(Wb_ + (size_t)(L >> 2) * Kst + k0 + (((L & 3) ^ ((L >> 3) & 3)) * 8),
             &Bs[b][L * 8]);
    }
  };
  // full pipelined pass over one operand pair, accumulating into acc
  auto gloop = [&](const u16* Ap, const u16* Wp, int Kst) {
    const u16* Ab_ = Ap + (size_t)(bm * BM) * Kst;
    const u16* Wb_ = Wp + (size_t)(bn * BN) * Kst;
    const int NT = Kst / BK;
    // entry guard: own LDS reads done + all waves past previous use
    asm volatile("s_waitcnt lgkmcnt(0)" ::: "memory");
    __builtin_amdgcn_s_barrier();
    __builtin_amdgcn_sched_barrier(0);
    for (int p = 0; p < NBUF - 1 && p < NT; p++) stage(Ab_, Wb_, Kst, p * BK, p);
    for (int t = 0; t < NT; t++) {
      int buf = t % NBUF;
      if (t + 1 < NT) waitvm<LPT>(); else waitvm<0>();  // tile t landed (in-order)
      __builtin_amdgcn_s_barrier();
      __builtin_amdgcn_sched_barrier(0);
      if (t + NBUF - 1 < NT) stage(Ab_, Wb_, Kst, (t + NBUF - 1) * BK,
                                   (t + NBUF - 1) % NBUF);
      s16x8 af[MF], bfr[NF];
      #pragma unroll
      for (int mi = 0; mi < MF; mi++) {
        int r = wr * WM + mi * 16 + c15;
        af[mi] = *(const s16x8*)&As[buf][r * BK + ((g ^ ((r >> 1) & 3)) << 3)];
      }
      #pragma unroll
      for (int ni = 0; ni < NF; ni++) {
        int r = wc * WN + ni * 16 + c15;
        bfr[ni] = *(const s16x8*)&Bs[buf][r * BK + ((g ^ ((r >> 1) & 3)) << 3)];
      }
      __builtin_amdgcn_s_setprio(1);
      #pragma unroll
      for (int mi = 0; mi < MF; mi++)
        #pragma unroll
        for (int ni = 0; ni < NF; ni++)
          acc[mi][ni] = mfma16(af[mi], bfr[ni], acc[mi][ni]);
      __builtin_amdgcn_s_setprio(0);
    }
  };
  gloop(A, W, K);
  if constexpr (EPI == 7) gloop(A2, W2, K2);
  #pragma unroll
  for (int mi = 0; mi < MF; mi++) {
    #pragma unroll
    for (int ni = 0; ni < NF; ni++) {
      int col = bn * BN + wc * WN + ni * 16 + c15;
      float bv = bias[col];
      if (EPI == 7) bv += 0.5f * bias2[col];
      #pragma unroll
      for (int j = 0; j < 4; j++) {
        int row = bm * BM + wr * WM + mi * 16 + g * 4 + j;
        size_t idx = (size_t)row * N + col;
        float v = acc[mi][ni][j] + bv;
        if (EPI == 0) {
          obf[idx] = f2bf(v);
        } else if (EPI == 2) {
          obf[idx] = f2bf(gelu_f(v));
        } else if (EPI == 3) {
          of[idx] = add1[idx] + bf2f(obf[idx]) + v;
        } else if (EPI == 7) {
          of[idx] = add1[idx] + v;
        } else if (EPI == 6) {
          // packed QKV: seg 0/1/2 -> Qp/Kp/Vp [whi][n][64]
          int seg = col >= 1536 ? 2 : (col >= 768 ? 1 : 0);
          int cc_ = col - seg * 768;
          int hh = cc_ >> 6, c = cc_ & 63;
          int t2 = row;
          int b = t2 >> 12, d = (t2 >> 8) & 15, hy = (t2 >> 4) & 15, wx = t2 & 15;
          int wi = (b << 3) | ((d >> 3) << 2) | ((hy >> 3) << 1) | (wx >> 3);
          int n = ((d & 7) << 6) | ((hy & 7) << 3) | (wx & 7);
          obf[(size_t)seg * (WHN * WHSZ) +
              ((size_t)(wi * NHEADS + hh) * 512 + n) * 64 + c] = f2bf(v);
        }
      }
    }
  }
}

// ---------------- transpose Vp[whi][n][c] -> Vt[whi][c][n] ----------------
__global__ __launch_bounds__(256) void repack_v(const u16* __restrict__ vp,
                                                u16* __restrict__ vt) {
  int whi = blockIdx.x;
  __shared__ u16 Vs[512 * 64];  // XOR-swizzled: slot(n,c) = n*64 + (c ^ (n&63))
  int tid = threadIdx.x;
  const u16* src = vp + (size_t)whi * WHSZ;
  for (int idx = tid; idx < 512 * 64; idx += 256) {
    int n = idx >> 6, c = idx & 63;
    Vs[(n << 6) | (c ^ (n & 63))] = src[idx];
  }
  __syncthreads();
  size_t base = (size_t)whi * WHSZ;
  #pragma unroll 1
  for (int i = 0; i < 32; i++) {
    int idx4 = tid + i * 256;  // 0..8191
    int c = idx4 >> 7, np = (idx4 & 127) << 2;
    ushort4 o;
    o.x = Vs[((np + 0) << 6) | (c ^ ((np + 0) & 63))];
    o.y = Vs[((np + 1) << 6) | (c ^ ((np + 1) & 63))];
    o.z = Vs[((np + 2) << 6) | (c ^ ((np + 2) & 63))];
    o.w = Vs[((np + 3) << 6) | (c ^ ((np + 3) & 63))];
    *(ushort4*)(vt + base + (size_t)c * 512 + np) = o;
  }
}

// ------- windowed attention: MFMA rel-pos prolog, exp2 softmax, counted-vmcnt ------
// grid: 768 blocks, blk = qblk*192 + whi (same whi -> same XCD L2)
// 4 waves x 32 q-rows (2 tiles of 16); 64-key chunks.
__global__ __launch_bounds__(256) void attn_win(const u16* __restrict__ Qp,
    const u16* __restrict__ Kp, const u16* __restrict__ vt,
    const u16* __restrict__ rpbf, u16* __restrict__ out) {
  int blk = blockIdx.x;
  int whi = blk % WHN, qblk = blk / WHN;
  int wi = whi / NHEADS, hh = whi % NHEADS;
  int tid = threadIdx.x;
  int wave = tid >> 6, lane = tid & 63;
  int g = lane >> 4, c15 = lane & 15;
  int n0 = qblk * 128 + wave * 32;
  __shared__ __align__(16) u16 Ks[2][4096];     // 64 rows x 64 u16, 16B-unit XOR-swizzled
  __shared__ __align__(16) u16 Vs[2][4096];     // 64 c-rows x 64 keys, same swizzle
  __shared__ float relf[4][32][16];             // 8KB: rel_d full table (xL2E)
  __shared__ __align__(16) u16 pool[4][16][64]; // 8KB: P staging (swizzled)
  const u16* qbase = Qp + (size_t)whi * WHSZ;
  const u16* kbase = Kp + (size_t)whi * WHSZ;
  const u16* vbase = vt + (size_t)whi * WHSZ;

  auto stage = [&](int kc, int buf) {
    #pragma unroll
    for (int i = 0; i < 2; i++) {
      int seg = wave * 2048 + i * 1024 + lane * 16;  // byte offset in 8KB buffer
      int r = seg >> 7, u = (seg >> 4) & 7;
      int su = (u ^ (r & 7)) << 3;                   // swizzled unit, u16 offset
      glds16(kbase + (size_t)(kc + r) * 64 + su, &Ks[buf][seg >> 1]);
      glds16(vbase + (size_t)r * 512 + kc + su, &Vs[buf][seg >> 1]);
    }
  };

  stage(0, 0);  // chunk 0 -> buf 0 (touches buffer 0 only)

  // Q A-fragments for the two 16-row tiles
  const u16* qbA = qbase + (size_t)(n0 + c15) * 64;
  const u16* qbB = qbase + (size_t)(n0 + 16 + c15) * 64;
  s16x8 aA0 = *(const s16x8*)(qbA + g * 8);
  s16x8 aA1 = *(const s16x8*)(qbA + 32 + g * 8);
  s16x8 aB0 = *(const s16x8*)(qbB + g * 8);
  s16x8 aB1 = *(const s16x8*)(qbB + 32 + g * 8);

  // rel-pos via MFMA: S_rel[q][t] = Q . RP^T (t = table row 0..14)
  // axis d -> relf (kept all loop); axes h,w -> transient scratch aliasing
  // K/V buffer 1 (not staged until after the first loop barrier -> race-free).
  float* scr = (wave < 2) ? (float*)&Ks[1][0] + wave * 1024
                          : (float*)&Vs[1][0] + (wave - 2) * 1024;
  int c15c = c15 < 14 ? c15 : 14;
  #pragma unroll
  for (int ax = 0; ax < 3; ax++) {
    const u16* tb = rpbf + ax * 960 + c15c * 64;
    s16x8 b0 = *(const s16x8*)(tb + g * 8);
    s16x8 b1 = *(const s16x8*)(tb + 32 + g * 8);
    f32x4 rA = {0.f, 0.f, 0.f, 0.f}, rB = {0.f, 0.f, 0.f, 0.f};
    rA = mfma16(aA0, b0, rA); rA = mfma16(aA1, b1, rA);
    rB = mfma16(aB0, b0, rB); rB = mfma16(aB1, b1, rB);
    #pragma unroll
    for (int j = 0; j < 4; j++) {
      float vA_ = rA[j] * L2E, vB_ = rB[j] * L2E;
      if (ax == 0) {
        relf[wave][g * 4 + j][c15] = vA_;
        relf[wave][16 + g * 4 + j][c15] = vB_;
      } else {
        scr[((ax - 1) * 32 + g * 4 + j) * 16 + c15] = vA_;
        scr[((ax - 1) * 32 + 16 + g * 4 + j) * 16 + c15] = vB_;
      }
    }
  }
  asm volatile("s_waitcnt lgkmcnt(0)" ::: "memory");
  __builtin_amdgcn_sched_barrier(0);

  // hoist rel_h + rel_w into registers; record rel_d column bases
  float rbA[4][4], rbB[4][4];
  int cdA[4], cdB[4];
  #pragma unroll
  for (int j = 0; j < 4; j++) {
    int rAi = g * 4 + j, rBi = 16 + g * 4 + j;
    int nA = n0 + rAi, nB = n0 + rBi;
    cdA[j] = (nA >> 6) + 7;  // in-loop col = cdA[j] - chunk
    cdB[j] = (nB >> 6) + 7;
    int kw = c15 & 7;
    float rwA = scr[(32 + rAi) * 16 + ((nA & 7) - kw + 7)];
    float rwB = scr[(32 + rBi) * 16 + ((nB & 7) - kw + 7)];
    #pragma unroll
    for (int cc = 0; cc < 4; cc++) {
      int kh = (cc * 2 + (c15 >> 3)) & 7;
      rbA[cc][j] = scr[rAi * 16 + (((nA >> 3) & 7) - kh + 7)] + rwA;
      rbB[cc][j] = scr[rBi * 16 + (((nB >> 3) & 7) - kh + 7)] + rwB;
    }
  }

  float mA = -1e30f, mB = -1e30f;   // log2-domain running maxima
  float lA[4] = {0.f, 0.f, 0.f, 0.f}, lB[4] = {0.f, 0.f, 0.f, 0.f};
  f32x4 oA[4] = {}, oB[4] = {};

  for (int c = 0; c < 8; c++) {
    int buf = c & 1;
    waitvm<0>();                      // chunk c landed (issued during compute c-1)
    __builtin_amdgcn_s_barrier();     // also fences scratch-alias before stage(1,..)
    __builtin_amdgcn_sched_barrier(0);
    if (c < 7) stage((c + 1) * 64, buf ^ 1);  // prefetch under compute(c)
    // ---- QK^T both tiles, K fragments loaded once ----
    f32x4 sA[4], sB[4];
    __builtin_amdgcn_s_setprio(1);
    #pragma unroll
    for (int cc = 0; cc < 4; cc++) {
      int r = cc * 16 + c15;
      const u16* kr = &Ks[buf][r * 64];
      s16x8 k0 = *(const s16x8*)(kr + ((g ^ (r & 7)) << 3));
      s16x8 k1 = *(const s16x8*)(kr + (((4 + g) ^ (r & 7)) << 3));
      f32x4 t0 = {0.f, 0.f, 0.f, 0.f};
      t0 = mfma16(aA0, k0, t0);
      sA[cc] = mfma16(aA1, k1, t0);
      f32x4 t1 = {0.f, 0.f, 0.f, 0.f};
      t1 = mfma16(aB0, k0, t1);
      sB[cc] = mfma16(aB1, k1, t1);
    }
    __builtin_amdgcn_s_setprio(0);
    // ---- scale (log2 domain) + rel-pos ----
    float rdA[4], rdB[4];
    #pragma unroll
    for (int j = 0; j < 4; j++) {
      rdA[j] = relf[wave][g * 4 + j][cdA[j] - c];
      rdB[j] = relf[wave][16 + g * 4 + j][cdB[j] - c];
    }
    #pragma unroll
    for (int cc = 0; cc < 4; cc++)
      #pragma unroll
      for (int j = 0; j < 4; j++) {
        sA[cc][j] = sA[cc][j] * SCL2 + (rdA[j] + rbA[cc][j]);
        sB[cc][j] = sB[cc][j] * SCL2 + (rdB[j] + rbB[cc][j]);
      }
    // ================= tile A: softmax + PV =================
    {
      float mx = fmaxf(fmaxf(fmaxf(sA[0][0], sA[0][1]), fmaxf(sA[0][2], sA[0][3])),
                       fmaxf(fmaxf(sA[1][0], sA[1][1]), fmaxf(sA[1][2], sA[1][3])));
      mx = fmaxf(mx, fmaxf(fmaxf(fmaxf(sA[2][0], sA[2][1]), fmaxf(sA[2][2], sA[2][3])),
                           fmaxf(fmaxf(sA[3][0], sA[3][1]), fmaxf(sA[3][2], sA[3][3]))));
      #pragma unroll
      for (int msk = 1; msk < 16; msk <<= 1) mx = fmaxf(mx, __shfl_xor(mx, msk));
      if (__any(mx > mA + 8.f)) {      // defer-max: p bounded by 2^8
        float mn = fmaxf(mA, mx);
        float corr = EXP2F(mA - mn);
        #pragma unroll
        for (int j = 0; j < 4; j++) lA[j] *= corr;
        #pragma unroll
        for (int cf = 0; cf < 4; cf++)
          #pragma unroll
          for (int j = 0; j < 4; j++) oA[cf][j] *= corr;
        mA = mn;
      }
      #pragma unroll
      for (int cc = 0; cc < 4; cc++)
        #pragma unroll
        for (int j = 0; j < 4; j++) {
          float p = EXP2F(sA[cc][j] - mA);
          lA[j] += p;
          int row = g * 4 + j;
          pool[wave][row][(((cc * 2 + (c15 >> 3)) ^ (row & 7)) << 3) | (c15 & 7)] =
              f2bf(p);
        }
      asm volatile("s_waitcnt lgkmcnt(0)" ::: "memory");
      __builtin_amdgcn_sched_barrier(0);
      s16x8 pa0 = *(const s16x8*)&pool[wave][c15][(g ^ (c15 & 7)) << 3];
      s16x8 pa1 = *(const s16x8*)&pool[wave][c15][((4 + g) ^ (c15 & 7)) << 3];
      __builtin_amdgcn_s_setprio(1);
      #pragma unroll
      for (int cf = 0; cf < 4; cf++) {
        int cv = cf * 16 + c15;
        const u16* vr = &Vs[buf][cv * 64];
        oA[cf] = mfma16(pa0, *(const s16x8*)(vr + ((g ^ (cv & 7)) << 3)), oA[cf]);
        oA[cf] = mfma16(pa1, *(const s16x8*)(vr + (((4 + g) ^ (cv & 7)) << 3)), oA[cf]);
      }
      __builtin_amdgcn_s_setprio(0);
    }
    // ================= tile B: softmax + PV =================
    {
      float mx = fmaxf(fmaxf(fmaxf(sB[0][0], sB[0][1]), fmaxf(sB[0][2], sB[0][3])),
                       fmaxf(fmaxf(sB[1][0], sB[1][1]), fmaxf(sB[1][2], sB[1][3])));
      mx = fmaxf(mx, fmaxf(fmaxf(fmaxf(sB[2][0], sB[2][1]), fmaxf(sB[2][2], sB[2][3])),
                           fmaxf(fmaxf(sB[3][0], sB[3][1]), fmaxf(sB[3][2], sB[3][3]))));
      #pragma unroll
      for (int msk = 1; msk < 16; msk <<= 1) mx = fmaxf(mx, __shfl_xor(mx, msk));
      if (__any(mx > mB + 8.f)) {
        float mn = fmaxf(mB, mx);
        float corr = EXP2F(mB - mn);
        #pragma unroll
        for (int j = 0; j < 4; j++) lB[j] *= corr;
        #pragma unroll
        for (int cf = 0; cf < 4; cf++)
          #pragma unroll
          for (int j = 0; j < 4; j++) oB[cf][j] *= corr;
        mB = mn;
      }
      #pragma unroll
      for (int cc = 0; cc < 4; cc++)
        #pragma unroll
        for (int j = 0; j < 4; j++) {
          float p = EXP2F(sB[cc][j] - mB);
          lB[j] += p;
          int row = g * 4 + j;
          pool[wave][row][(((cc * 2 + (c15 >> 3)) ^ (row & 7)) << 3) | (c15 & 7)] =
              f2bf(p);
        }
      asm volatile("s_waitcnt lgkmcnt(0)" ::: "memory");
      __builtin_amdgcn_sched_barrier(0);
      s16x8 pa0 = *(const s16x8*)&pool[wave][c15][(g ^ (c15 & 7)) << 3];
      s16x8 pa1 = *(const s16x8*)&pool[wave][c15][((4 + g) ^ (c15 & 7)) << 3];
      __builtin_amdgcn_s_setprio(1);
      #pragma unroll
      for (int cf = 0; cf < 4; cf++) {
        int cv = cf * 16 + c15;
        const u16* vr = &Vs[buf][cv * 64];
        oB[cf] = mfma16(pa0, *(const s16x8*)(vr + ((g ^ (cv & 7)) << 3)), oB[cf]);
        oB[cf] = mfma16(pa1, *(const s16x8*)(vr + (((4 + g) ^ (cv & 7)) << 3)), oB[cf]);
      }
      __builtin_amdgcn_s_setprio(0);
    }
  }
  // epilogue: reduce denominators across 16 key-lanes, normalize, store both tiles
  #pragma unroll
  for (int j = 0; j < 4; j++) {
    #pragma unroll
    for (int msk = 1; msk < 16; msk <<= 1) {
      lA[j] += __shfl_xor(lA[j], msk);
      lB[j] += __shfl_xor(lB[j], msk);
    }
    lA[j] = 1.0f / lA[j];
    lB[j] = 1.0f / lB[j];
  }
  #pragma unroll
  for (int j = 0; j < 4; j++) {
    int tA = tok_of(wi, n0 + g * 4 + j);
    int tB = tok_of(wi, n0 + 16 + g * 4 + j);
    u16* orA = out + (size_t)tA * NDIM + hh * 64;
    u16* orB = out + (size_t)tB * NDIM + hh * 64;
    #pragma unroll
    for (int cf = 0; cf < 4; cf++) {
      orA[cf * 16 + c15] = f2bf(oA[cf][j] * lA[j]);
      orB[cf * 16 + c15] = f2bf(oB[cf][j] * lB[j]);
    }
  }
}

extern "C" void kernel_launch(void* const* d_in, const int* in_sizes, int n_in,
                              void* d_out, int out_size, void* d_ws, size_t ws_size,
                              hipStream_t stream) {
  const float* x     = (const float*)d_in[0];
  const float* ln1_g = (const float*)d_in[1];
  const float* ln1_b = (const float*)d_in[2];
  const float* qkv_w = (const float*)d_in[3];
  const float* qkv_b = (const float*)d_in[4];
  const float* rpd   = (const float*)d_in[5];
  const float* rph   = (const float*)d_in[6];
  const float* rpw   = (const float*)d_in[7];
  const float* proj_w = (const float*)d_in[8];
  const float* proj_b = (const float*)d_in[9];
  const float* aa1_w = (const float*)d_in[10];
  const float* aa1_b = (const float*)d_in[11];
  const float* aa2_w = (const float*)d_in[12];
  const float* aa2_b = (const float*)d_in[13];
  const float* ln2_g = (const float*)d_in[14];
  const float* ln2_b = (const float*)d_in[15];
  const float* mlp1_w = (const float*)d_in[16];
  const float* mlp1_b = (const float*)d_in[17];
  const float* mlp2_w = (const float*)d_in[18];
  const float* mlp2_b = (const float*)d_in[19];
  const float* ma1_w = (const float*)d_in[20];
  const float* ma1_b = (const float*)d_in[21];
  const float* ma2_w = (const float*)d_in[22];
  const float* ma2_b = (const float*)d_in[23];
  float* out = (float*)d_out;
  char* ws = (char*)d_ws;

  // arena (explicit lifetimes; total ~157 MB)
  u16* wqkv  = (u16*)(ws + 0);          // 3538944 B
  u16* wproj = (u16*)(ws + 3538944);    // 1179648
  u16* wmlp1 = (u16*)(ws + 4718592);    // 4718592
  u16* wmlp2 = (u16*)(ws + 9437184);    // 4718592
  u16* waa1  = (u16*)(ws + 14155776);   // 294912
  u16* waa2  = (u16*)(ws + 14450688);   // 294912
  u16* wma1  = (u16*)(ws + 14745600);   // 294912
  u16* wma2  = (u16*)(ws + 15040512);   // 294912 (x0.5 folded)
  u16* h1    = (u16*)(ws + 15335424);   // 12.58 MB: LN1 out, then reused as attn_out
  u16* attno = h1;
  u16* qkvp  = (u16*)(ws + 27918336);   // 37.75 MB: packed Qp|Kp|Vp, later p_bf
  u16* p_bf  = (u16*)(ws + 53084160);
  u16* vtp   = (u16*)(ws + 65667072);   // 12.58 MB: V_t, then hn
  u16* hn    = vtp;
  float* h_f = (float*)(ws + 78249984); // 25.17 MB
  u16* ah    = (u16*)(ws + 103415808);  // adapter hidden, then mlp hidden (50.33 MB)
  u16* mlph  = ah;
  u16* mah   = (u16*)(ws + 153747456);  // 3.15 MB (used after attn)
  // rpbf aliases mah head: written by conv (first), read by attn, dead before ma1
  u16* rpbf  = (u16*)(ws + 153747456);  // 5760 B transient
  (void)ws_size; (void)in_sizes; (void)n_in; (void)out_size;

  u16* Qp = qkvp;
  u16* Kp = qkvp + (size_t)WHN * WHSZ;
  u16* Vp = qkvp + 2 * (size_t)WHN * WHSZ;

  WConv wc;
  for (int i = 0; i < 11; i++) wc.scl[i] = 1.0f;
  wc.src[0] = qkv_w;  wc.dst[0] = wqkv;  wc.n[0] = 2304 * 768;
  wc.src[1] = proj_w; wc.dst[1] = wproj; wc.n[1] = 768 * 768;
  wc.src[2] = mlp1_w; wc.dst[2] = wmlp1; wc.n[2] = 3072 * 768;
  wc.src[3] = mlp2_w; wc.dst[3] = wmlp2; wc.n[3] = 768 * 3072;
  wc.src[4] = aa1_w;  wc.dst[4] = waa1;  wc.n[4] = 192 * 768;
  wc.src[5] = aa2_w;  wc.dst[5] = waa2;  wc.n[5] = 768 * 192;
  wc.src[6] = ma1_w;  wc.dst[6] = wma1;  wc.n[6] = 192 * 768;
  wc.src[7] = ma2_w;  wc.dst[7] = wma2;  wc.n[7] = 768 * 192;
  wc.scl[7] = 0.5f;   // ADAPT_SCALE folded into wma2
  wc.src[8] = rpd;    wc.dst[8] = rpbf;  wc.n[8] = 15 * 64;
  wc.src[9] = rph;    wc.dst[9] = rpbf + 960;  wc.n[9] = 15 * 64;
  wc.src[10] = rpw;   wc.dst[10] = rpbf + 1920; wc.n[10] = 15 * 64;
  conv_weights<<<1024, 256, 0, stream>>>(wc);

  ln_bf16<<<TOK, 256, 0, stream>>>(x, ln1_g, ln1_b, h1);
  // qkv: 64x64 wave tiles (4x2 wave grid), 2 blocks/CU
  gemm_bf16<256, 128, 512, 3, 6><<<dim3(32, 18), 512, 0, stream>>>(
      h1, wqkv, qkv_b, TOK, 2304, 768, qkvp, nullptr, nullptr,
      nullptr, nullptr, 0, nullptr);
  repack_v<<<192, 256, 0, stream>>>(Vp, vtp);
  attn_win<<<768, 256, 0, stream>>>(Qp, Kp, vtp, rpbf, attno);
  // N=768 GEMMs: 64x96 wave tiles, grid 256 = exactly 1 block/CU
  gemm_bf16<128, 192, 256, 3, 0><<<dim3(64, 4), 256, 0, stream>>>(
      attno, wproj, proj_b, TOK, 768, 768, p_bf, nullptr, nullptr,
      nullptr, nullptr, 0, nullptr);
  gemm_bf16<64, 64, 256, 3, 2><<<dim3(128, 3), 256, 0, stream>>>(
      p_bf, waa1, aa1_b, TOK, 192, 768, ah, nullptr, nullptr,
      nullptr, nullptr, 0, nullptr);
  gemm_bf16<128, 192, 256, 3, 3><<<dim3(64, 4), 256, 0, stream>>>(
      ah, waa2, aa2_b, TOK, 768, 192, p_bf, h_f, x,
      nullptr, nullptr, 0, nullptr);
  ln_bf16<<<TOK, 256, 0, stream>>>(h_f, ln2_g, ln2_b, hn);
  gemm_bf16<64, 64, 256, 3, 2><<<dim3(128, 3), 256, 0, stream>>>(
      hn, wma1, ma1_b, TOK, 192, 768, mah, nullptr, nullptr,
      nullptr, nullptr, 0, nullptr);
  gemm_bf16<256, 128, 512, 3, 2><<<dim3(32, 24), 512, 0, stream>>>(
      hn, wmlp1, mlp1_b, TOK, 3072, 768, mlph, nullptr, nullptr,
      nullptr, nullptr, 0, nullptr);
  // fused: out = h_f + (mlph@wmlp2^T + b) + 0.5*(mah@wma2^T + b2)  (0.5 in wma2)
  gemm_bf16<128, 192, 256, 3, 7><<<dim3(64, 4), 256, 0, stream>>>(
      mlph, wmlp2, mlp2_b, TOK, 768, 3072, nullptr, out, h_f,
      mah, wma2, 192, ma2_b);
}

// Round 14
// 323.009 us; speedup vs baseline: 1.0916x; 1.0916x over previous
//
#include <hip/hip_runtime.h>

typedef unsigned short u16;
typedef __attribute__((ext_vector_type(4))) float f32x4;
typedef __attribute__((ext_vector_type(8))) short s16x8;

#define TOK 8192
#define NDIM 768
#define NHEADS 12
#define WHN 192            // window-heads
#define WHSZ 32768         // 512*64 elements per window-head plane
#define L2E 1.4426950408889634f
#define SCL2 (0.125f * L2E)

#if __has_builtin(__builtin_amdgcn_exp2f)
#define EXP2F __builtin_amdgcn_exp2f
#else
#define EXP2F exp2f
#endif

__device__ __forceinline__ u16 f2bf(float f) {
  union { float f; unsigned u; } x; x.f = f;
  unsigned r = x.u + 0x7fffu + ((x.u >> 16) & 1u);
  return (u16)(r >> 16);
}
__device__ __forceinline__ float bf2f(u16 u) {
  union { unsigned u; float f; } x; x.u = ((unsigned)u) << 16;
  return x.f;
}
// fast erf-based exact GELU (A&S 7.1.26, |err| <= 1.5e-7)
__device__ __forceinline__ float gelu_f(float v) {
  float z = fabsf(v) * 0.70710678118654752f;
  float t = __builtin_amdgcn_rcpf(1.0f + 0.3275911f * z);
  float poly = t * (0.254829592f +
               t * (-0.284496736f +
               t * (1.421413741f +
               t * (-1.453152027f + t * 1.061405429f))));
  float erfv = 1.0f - poly * __expf(-z * z);
  erfv = copysignf(erfv, v);
  return 0.5f * v * (1.0f + erfv);
}
__device__ __forceinline__ f32x4 mfma16(s16x8 a, s16x8 b, f32x4 c) {
  return __builtin_amdgcn_mfma_f32_16x16x32_bf16(a, b, c, 0, 0, 0);
}
__device__ __forceinline__ void glds16(const u16* g, u16* l) {
  __builtin_amdgcn_global_load_lds(
      (const __attribute__((address_space(1))) unsigned int*)g,
      (__attribute__((address_space(3))) unsigned int*)l, 16, 0, 0);
}
// counted vmcnt wait (literal immediates), with scheduling fence (rule #18)
template<int N> __device__ __forceinline__ void waitvm() {
  if constexpr (N == 0)      asm volatile("s_waitcnt vmcnt(0)" ::: "memory");
  else if constexpr (N == 2) asm volatile("s_waitcnt vmcnt(2)" ::: "memory");
  else if constexpr (N == 3) asm volatile("s_waitcnt vmcnt(3)" ::: "memory");
  else if constexpr (N == 4) asm volatile("s_waitcnt vmcnt(4)" ::: "memory");
  else if constexpr (N == 5) asm volatile("s_waitcnt vmcnt(5)" ::: "memory");
  else if constexpr (N == 6) asm volatile("s_waitcnt vmcnt(6)" ::: "memory");
  else if constexpr (N == 8) asm volatile("s_waitcnt vmcnt(8)" ::: "memory");
  __builtin_amdgcn_sched_barrier(0);
}
// window (wi in [0,16), n in [0,512)) -> flat spatial token index
__device__ __forceinline__ int tok_of(int wi, int n) {
  int b = wi >> 3;
  int d = (((wi >> 2) & 1) << 3) | (n >> 6);
  int h = (((wi >> 1) & 1) << 3) | ((n >> 3) & 7);
  int w = ((wi & 1) << 3) | (n & 7);
  return (b << 12) | (d << 8) | (h << 4) | w;
}

// ------ fp32 -> bf16 conversion (weights + rel-pos tables), optional scale ------
struct WConv {
  const float* src[11];
  u16* dst[11];
  int n[11];
  float scl[11];
};
__global__ __launch_bounds__(256) void conv_weights(WConv a) {
  int stride = gridDim.x * blockDim.x;
  int t0 = blockIdx.x * blockDim.x + threadIdx.x;
  for (int s = 0; s < 11; s++) {
    const float4* src = (const float4*)a.src[s];
    u16* dst = a.dst[s];
    float sc = a.scl[s];
    int n4 = a.n[s] >> 2;
    for (int i = t0; i < n4; i += stride) {
      float4 v = src[i];
      ushort4 o;
      o.x = f2bf(v.x * sc); o.y = f2bf(v.y * sc);
      o.z = f2bf(v.z * sc); o.w = f2bf(v.w * sc);
      *(ushort4*)(dst + 4 * (size_t)i) = o;
    }
  }
}

// ---------------- LayerNorm (fp32 in -> bf16 out) ----------------
__global__ __launch_bounds__(256) void ln_bf16(const float* __restrict__ in,
    const float* __restrict__ gamma, const float* __restrict__ beta,
    u16* __restrict__ out) {
  const int row = blockIdx.x;
  const int tid = threadIdx.x;
  const float* xr = in + (size_t)row * NDIM;
  float v0 = xr[tid], v1 = xr[tid + 256], v2 = xr[tid + 512];
  float s = v0 + v1 + v2;
  float q = v0 * v0 + v1 * v1 + v2 * v2;
  for (int o = 32; o; o >>= 1) { s += __shfl_down(s, o); q += __shfl_down(q, o); }
  __shared__ float ss[4], sq[4];
  int wave = tid >> 6, lane = tid & 63;
  if (lane == 0) { ss[wave] = s; sq[wave] = q; }
  __syncthreads();
  s = ss[0] + ss[1] + ss[2] + ss[3];
  q = sq[0] + sq[1] + sq[2] + sq[3];
  float mean = s * (1.0f / 768.0f);
  float var = q * (1.0f / 768.0f) - mean * mean;
  float rstd = rsqrtf(var + 1e-5f);
  u16* orow = out + (size_t)row * NDIM;
  float v[3] = {v0, v1, v2};
  #pragma unroll
  for (int i = 0; i < 3; i++) {
    int c = tid + i * 256;
    orow[c] = f2bf((v[i] - mean) * rstd * gamma[c] + beta[c]);
  }
}

// ---- GEMM: C[M,N] = A[M,K](bf16) * W[N,K]^T(bf16) + bias ----
// NBUF-buffer rotation, counted vmcnt, 1 raw barrier per K-step.
// Wave grid: TPB=256 -> 2x2; TPB=512 & BM>=256 -> 4x2 (tile 64x64);
//            TPB=512 & BM=128 -> 2x4? No: WROWS chosen so wave tile rows>=32.
//   Here: WROWS = (TPB==512 && BM>=256) ? 4 : (TPB==512 ? 4 : 2) -- for BM=128
//   TPB=512 gives WROWS=4 -> wave tile 32x64 (same FLOP/LDS-byte as 64x32,
//   but 3 blocks/CU = 24 waves/CU for latency hiding).
// LDS swizzle (verified conflict-free): store source unit (L&3)^((L>>3)&3)
// at slot L&3; read g^((r>>1)&3). 2 lanes/bank = free.
// EPI 0: bf16 store; 2: gelu->bf16; 3: of=add1+bf2f(obf)+v (bf16 residual);
// EPI 6: packed QKV; EPI 7: dual-K fused (mlp2+ma2)
template<int BM, int BN, int TPB, int NBUF, int EPI>
__global__ __launch_bounds__(TPB) void gemm_bf16(
    const u16* __restrict__ A, const u16* __restrict__ W,
    const float* __restrict__ bias, int M, int N, int K,
    u16* __restrict__ obf, float* __restrict__ of,
    const float* __restrict__ add1,
    const u16* __restrict__ A2, const u16* __restrict__ W2, int K2,
    const float* __restrict__ bias2) {
  constexpr int BK = 32;
  constexpr int WROWS = (TPB == 512) ? 4 : 2;
  constexpr int WCOLS = TPB / 64 / WROWS;   // 2
  constexpr int WM = BM / WROWS, WN = BN / WCOLS;
  constexpr int MF = WM / 16, NF = WN / 16;
  constexpr int ACH = BM * BK / (8 * TPB);  // 16B chunks per thread for A
  constexpr int BCH = BN * BK / (8 * TPB);
  constexpr int LPT = ACH + BCH;            // glds per thread per tile
  __shared__ __align__(16) u16 As[NBUF][BM * BK];
  __shared__ __align__(16) u16 Bs[NBUF][BN * BK];
  const int bm = blockIdx.x, bn = blockIdx.y;
  const int tid = threadIdx.x;
  const int wave = tid >> 6, lane = tid & 63;
  const int wr = wave / WCOLS, wc = wave % WCOLS;
  const int g = lane >> 4, c15 = lane & 15;
  f32x4 acc[MF][NF] = {};
  // stage: linear LDS dest, 8-phase XOR-swizzled global source
  auto stage = [&](const u16* Ab_, const u16* Wb_, int Kst, int k0, int b) {
    #pragma unroll
    for (int i = 0; i < ACH; i++) {
      int L = i * TPB + tid;  // row = L>>2, unit = L&3, swz = u ^ ((row>>1)&3)
      glds16(Ab_ + (size_t)(L >> 2) * Kst + k0 + (((L & 3) ^ ((L >> 3) & 3)) * 8),
             &As[b][L * 8]);
    }
    #pragma unroll
    for (int i = 0; i < BCH; i++) {
      int L = i * TPB + tid;
      glds16(Wb_ + (size_t)(L >> 2) * Kst + k0 + (((L & 3) ^ ((L >> 3) & 3)) * 8),
             &Bs[b][L * 8]);
    }
  };
  // full pipelined pass over one operand pair, accumulating into acc
  auto gloop = [&](const u16* Ap, const u16* Wp, int Kst) {
    const u16* Ab_ = Ap + (size_t)(bm * BM) * Kst;
    const u16* Wb_ = Wp + (size_t)(bn * BN) * Kst;
    const int NT = Kst / BK;
    // entry guard: own LDS reads done + all waves past previous use
    asm volatile("s_waitcnt lgkmcnt(0)" ::: "memory");
    __builtin_amdgcn_s_barrier();
    __builtin_amdgcn_sched_barrier(0);
    for (int p = 0; p < NBUF - 1 && p < NT; p++) stage(Ab_, Wb_, Kst, p * BK, p);
    for (int t = 0; t < NT; t++) {
      int buf = t % NBUF;
      if (t + 1 < NT) waitvm<LPT>(); else waitvm<0>();  // tile t landed (in-order)
      __builtin_amdgcn_s_barrier();
      __builtin_amdgcn_sched_barrier(0);
      if (t + NBUF - 1 < NT) stage(Ab_, Wb_, Kst, (t + NBUF - 1) * BK,
                                   (t + NBUF - 1) % NBUF);
      s16x8 af[MF], bfr[NF];
      #pragma unroll
      for (int mi = 0; mi < MF; mi++) {
        int r = wr * WM + mi * 16 + c15;
        af[mi] = *(const s16x8*)&As[buf][r * BK + ((g ^ ((r >> 1) & 3)) << 3)];
      }
      #pragma unroll
      for (int ni = 0; ni < NF; ni++) {
        int r = wc * WN + ni * 16 + c15;
        bfr[ni] = *(const s16x8*)&Bs[buf][r * BK + ((g ^ ((r >> 1) & 3)) << 3)];
      }
      __builtin_amdgcn_s_setprio(1);
      #pragma unroll
      for (int mi = 0; mi < MF; mi++)
        #pragma unroll
        for (int ni = 0; ni < NF; ni++)
          acc[mi][ni] = mfma16(af[mi], bfr[ni], acc[mi][ni]);
      __builtin_amdgcn_s_setprio(0);
    }
  };
  gloop(A, W, K);
  if constexpr (EPI == 7) gloop(A2, W2, K2);
  #pragma unroll
  for (int mi = 0; mi < MF; mi++) {
    #pragma unroll
    for (int ni = 0; ni < NF; ni++) {
      int col = bn * BN + wc * WN + ni * 16 + c15;
      float bv = bias[col];
      if (EPI == 7) bv += 0.5f * bias2[col];
      #pragma unroll
      for (int j = 0; j < 4; j++) {
        int row = bm * BM + wr * WM + mi * 16 + g * 4 + j;
        size_t idx = (size_t)row * N + col;
        float v = acc[mi][ni][j] + bv;
        if (EPI == 0) {
          obf[idx] = f2bf(v);
        } else if (EPI == 2) {
          obf[idx] = f2bf(gelu_f(v));
        } else if (EPI == 3) {
          of[idx] = add1[idx] + bf2f(obf[idx]) + v;
        } else if (EPI == 7) {
          of[idx] = add1[idx] + v;
        } else if (EPI == 6) {
          // packed QKV: seg 0/1/2 -> Qp/Kp/Vp [whi][n][64]
          int seg = col >= 1536 ? 2 : (col >= 768 ? 1 : 0);
          int cc_ = col - seg * 768;
          int hh = cc_ >> 6, c = cc_ & 63;
          int t2 = row;
          int b = t2 >> 12, d = (t2 >> 8) & 15, hy = (t2 >> 4) & 15, wx = t2 & 15;
          int wi = (b << 3) | ((d >> 3) << 2) | ((hy >> 3) << 1) | (wx >> 3);
          int n = ((d & 7) << 6) | ((hy & 7) << 3) | (wx & 7);
          obf[(size_t)seg * (WHN * WHSZ) +
              ((size_t)(wi * NHEADS + hh) * 512 + n) * 64 + c] = f2bf(v);
        }
      }
    }
  }
}

// ---------------- transpose Vp[whi][n][c] -> Vt[whi][c][n] ----------------
__global__ __launch_bounds__(256) void repack_v(const u16* __restrict__ vp,
                                                u16* __restrict__ vt) {
  int whi = blockIdx.x;
  __shared__ u16 Vs[512 * 64];  // XOR-swizzled: slot(n,c) = n*64 + (c ^ (n&63))
  int tid = threadIdx.x;
  const u16* src = vp + (size_t)whi * WHSZ;
  for (int idx = tid; idx < 512 * 64; idx += 256) {
    int n = idx >> 6, c = idx & 63;
    Vs[(n << 6) | (c ^ (n & 63))] = src[idx];
  }
  __syncthreads();
  size_t base = (size_t)whi * WHSZ;
  #pragma unroll 1
  for (int i = 0; i < 32; i++) {
    int idx4 = tid + i * 256;  // 0..8191
    int c = idx4 >> 7, np = (idx4 & 127) << 2;
    ushort4 o;
    o.x = Vs[((np + 0) << 6) | (c ^ ((np + 0) & 63))];
    o.y = Vs[((np + 1) << 6) | (c ^ ((np + 1) & 63))];
    o.z = Vs[((np + 2) << 6) | (c ^ ((np + 2) & 63))];
    o.w = Vs[((np + 3) << 6) | (c ^ ((np + 3) & 63))];
    *(ushort4*)(vt + base + (size_t)c * 512 + np) = o;
  }
}

// ------- windowed attention: MFMA rel-pos prolog, exp2 softmax, counted-vmcnt ------
// grid: 768 blocks, blk = qblk*192 + whi (same whi -> same XCD L2)
// 4 waves x 32 q-rows (2 tiles of 16); 64-key chunks.
__global__ __launch_bounds__(256) void attn_win(const u16* __restrict__ Qp,
    const u16* __restrict__ Kp, const u16* __restrict__ vt,
    const u16* __restrict__ rpbf, u16* __restrict__ out) {
  int blk = blockIdx.x;
  int whi = blk % WHN, qblk = blk / WHN;
  int wi = whi / NHEADS, hh = whi % NHEADS;
  int tid = threadIdx.x;
  int wave = tid >> 6, lane = tid & 63;
  int g = lane >> 4, c15 = lane & 15;
  int n0 = qblk * 128 + wave * 32;
  __shared__ __align__(16) u16 Ks[2][4096];     // 64 rows x 64 u16, 16B-unit XOR-swizzled
  __shared__ __align__(16) u16 Vs[2][4096];     // 64 c-rows x 64 keys, same swizzle
  __shared__ float relf[4][32][16];             // 8KB: rel_d full table (xL2E)
  __shared__ __align__(16) u16 pool[4][16][64]; // 8KB: P staging (swizzled)
  const u16* qbase = Qp + (size_t)whi * WHSZ;
  const u16* kbase = Kp + (size_t)whi * WHSZ;
  const u16* vbase = vt + (size_t)whi * WHSZ;

  auto stage = [&](int kc, int buf) {
    #pragma unroll
    for (int i = 0; i < 2; i++) {
      int seg = wave * 2048 + i * 1024 + lane * 16;  // byte offset in 8KB buffer
      int r = seg >> 7, u = (seg >> 4) & 7;
      int su = (u ^ (r & 7)) << 3;                   // swizzled unit, u16 offset
      glds16(kbase + (size_t)(kc + r) * 64 + su, &Ks[buf][seg >> 1]);
      glds16(vbase + (size_t)r * 512 + kc + su, &Vs[buf][seg >> 1]);
    }
  };

  stage(0, 0);  // chunk 0 -> buf 0 (touches buffer 0 only)

  // Q A-fragments for the two 16-row tiles
  const u16* qbA = qbase + (size_t)(n0 + c15) * 64;
  const u16* qbB = qbase + (size_t)(n0 + 16 + c15) * 64;
  s16x8 aA0 = *(const s16x8*)(qbA + g * 8);
  s16x8 aA1 = *(const s16x8*)(qbA + 32 + g * 8);
  s16x8 aB0 = *(const s16x8*)(qbB + g * 8);
  s16x8 aB1 = *(const s16x8*)(qbB + 32 + g * 8);

  // rel-pos via MFMA: S_rel[q][t] = Q . RP^T (t = table row 0..14)
  // axis d -> relf (kept all loop); axes h,w -> transient scratch aliasing
  // K/V buffer 1 (not staged until after the first loop barrier -> race-free).
  float* scr = (wave < 2) ? (float*)&Ks[1][0] + wave * 1024
                          : (float*)&Vs[1][0] + (wave - 2) * 1024;
  int c15c = c15 < 14 ? c15 : 14;
  #pragma unroll
  for (int ax = 0; ax < 3; ax++) {
    const u16* tb = rpbf + ax * 960 + c15c * 64;
    s16x8 b0 = *(const s16x8*)(tb + g * 8);
    s16x8 b1 = *(const s16x8*)(tb + 32 + g * 8);
    f32x4 rA = {0.f, 0.f, 0.f, 0.f}, rB = {0.f, 0.f, 0.f, 0.f};
    rA = mfma16(aA0, b0, rA); rA = mfma16(aA1, b1, rA);
    rB = mfma16(aB0, b0, rB); rB = mfma16(aB1, b1, rB);
    #pragma unroll
    for (int j = 0; j < 4; j++) {
      float vA_ = rA[j] * L2E, vB_ = rB[j] * L2E;
      if (ax == 0) {
        relf[wave][g * 4 + j][c15] = vA_;
        relf[wave][16 + g * 4 + j][c15] = vB_;
      } else {
        scr[((ax - 1) * 32 + g * 4 + j) * 16 + c15] = vA_;
        scr[((ax - 1) * 32 + 16 + g * 4 + j) * 16 + c15] = vB_;
      }
    }
  }
  asm volatile("s_waitcnt lgkmcnt(0)" ::: "memory");
  __builtin_amdgcn_sched_barrier(0);

  // hoist rel_h + rel_w into registers; record rel_d column bases
  float rbA[4][4], rbB[4][4];
  int cdA[4], cdB[4];
  #pragma unroll
  for (int j = 0; j < 4; j++) {
    int rAi = g * 4 + j, rBi = 16 + g * 4 + j;
    int nA = n0 + rAi, nB = n0 + rBi;
    cdA[j] = (nA >> 6) + 7;  // in-loop col = cdA[j] - chunk
    cdB[j] = (nB >> 6) + 7;
    int kw = c15 & 7;
    float rwA = scr[(32 + rAi) * 16 + ((nA & 7) - kw + 7)];
    float rwB = scr[(32 + rBi) * 16 + ((nB & 7) - kw + 7)];
    #pragma unroll
    for (int cc = 0; cc < 4; cc++) {
      int kh = (cc * 2 + (c15 >> 3)) & 7;
      rbA[cc][j] = scr[rAi * 16 + (((nA >> 3) & 7) - kh + 7)] + rwA;
      rbB[cc][j] = scr[rBi * 16 + (((nB >> 3) & 7) - kh + 7)] + rwB;
    }
  }

  float mA = -1e30f, mB = -1e30f;   // log2-domain running maxima
  float lA[4] = {0.f, 0.f, 0.f, 0.f}, lB[4] = {0.f, 0.f, 0.f, 0.f};
  f32x4 oA[4] = {}, oB[4] = {};

  for (int c = 0; c < 8; c++) {
    int buf = c & 1;
    waitvm<0>();                      // chunk c landed (issued during compute c-1)
    __builtin_amdgcn_s_barrier();     // also fences scratch-alias before stage(1,..)
    __builtin_amdgcn_sched_barrier(0);
    if (c < 7) stage((c + 1) * 64, buf ^ 1);  // prefetch under compute(c)
    // ---- QK^T both tiles, K fragments loaded once ----
    f32x4 sA[4], sB[4];
    __builtin_amdgcn_s_setprio(1);
    #pragma unroll
    for (int cc = 0; cc < 4; cc++) {
      int r = cc * 16 + c15;
      const u16* kr = &Ks[buf][r * 64];
      s16x8 k0 = *(const s16x8*)(kr + ((g ^ (r & 7)) << 3));
      s16x8 k1 = *(const s16x8*)(kr + (((4 + g) ^ (r & 7)) << 3));
      f32x4 t0 = {0.f, 0.f, 0.f, 0.f};
      t0 = mfma16(aA0, k0, t0);
      sA[cc] = mfma16(aA1, k1, t0);
      f32x4 t1 = {0.f, 0.f, 0.f, 0.f};
      t1 = mfma16(aB0, k0, t1);
      sB[cc] = mfma16(aB1, k1, t1);
    }
    __builtin_amdgcn_s_setprio(0);
    // ---- scale (log2 domain) + rel-pos ----
    float rdA[4], rdB[4];
    #pragma unroll
    for (int j = 0; j < 4; j++) {
      rdA[j] = relf[wave][g * 4 + j][cdA[j] - c];
      rdB[j] = relf[wave][16 + g * 4 + j][cdB[j] - c];
    }
    #pragma unroll
    for (int cc = 0; cc < 4; cc++)
      #pragma unroll
      for (int j = 0; j < 4; j++) {
        sA[cc][j] = sA[cc][j] * SCL2 + (rdA[j] + rbA[cc][j]);
        sB[cc][j] = sB[cc][j] * SCL2 + (rdB[j] + rbB[cc][j]);
      }
    // ================= tile A: softmax + PV =================
    {
      float mx = fmaxf(fmaxf(fmaxf(sA[0][0], sA[0][1]), fmaxf(sA[0][2], sA[0][3])),
                       fmaxf(fmaxf(sA[1][0], sA[1][1]), fmaxf(sA[1][2], sA[1][3])));
      mx = fmaxf(mx, fmaxf(fmaxf(fmaxf(sA[2][0], sA[2][1]), fmaxf(sA[2][2], sA[2][3])),
                           fmaxf(fmaxf(sA[3][0], sA[3][1]), fmaxf(sA[3][2], sA[3][3]))));
      #pragma unroll
      for (int msk = 1; msk < 16; msk <<= 1) mx = fmaxf(mx, __shfl_xor(mx, msk));
      if (__any(mx > mA + 8.f)) {      // defer-max: p bounded by 2^8
        float mn = fmaxf(mA, mx);
        float corr = EXP2F(mA - mn);
        #pragma unroll
        for (int j = 0; j < 4; j++) lA[j] *= corr;
        #pragma unroll
        for (int cf = 0; cf < 4; cf++)
          #pragma unroll
          for (int j = 0; j < 4; j++) oA[cf][j] *= corr;
        mA = mn;
      }
      #pragma unroll
      for (int cc = 0; cc < 4; cc++)
        #pragma unroll
        for (int j = 0; j < 4; j++) {
          float p = EXP2F(sA[cc][j] - mA);
          lA[j] += p;
          int row = g * 4 + j;
          pool[wave][row][(((cc * 2 + (c15 >> 3)) ^ (row & 7)) << 3) | (c15 & 7)] =
              f2bf(p);
        }
      asm volatile("s_waitcnt lgkmcnt(0)" ::: "memory");
      __builtin_amdgcn_sched_barrier(0);
      s16x8 pa0 = *(const s16x8*)&pool[wave][c15][(g ^ (c15 & 7)) << 3];
      s16x8 pa1 = *(const s16x8*)&pool[wave][c15][((4 + g) ^ (c15 & 7)) << 3];
      __builtin_amdgcn_s_setprio(1);
      #pragma unroll
      for (int cf = 0; cf < 4; cf++) {
        int cv = cf * 16 + c15;
        const u16* vr = &Vs[buf][cv * 64];
        oA[cf] = mfma16(pa0, *(const s16x8*)(vr + ((g ^ (cv & 7)) << 3)), oA[cf]);
        oA[cf] = mfma16(pa1, *(const s16x8*)(vr + (((4 + g) ^ (cv & 7)) << 3)), oA[cf]);
      }
      __builtin_amdgcn_s_setprio(0);
    }
    // ================= tile B: softmax + PV =================
    {
      float mx = fmaxf(fmaxf(fmaxf(sB[0][0], sB[0][1]), fmaxf(sB[0][2], sB[0][3])),
                       fmaxf(fmaxf(sB[1][0], sB[1][1]), fmaxf(sB[1][2], sB[1][3])));
      mx = fmaxf(mx, fmaxf(fmaxf(fmaxf(sB[2][0], sB[2][1]), fmaxf(sB[2][2], sB[2][3])),
                           fmaxf(fmaxf(sB[3][0], sB[3][1]), fmaxf(sB[3][2], sB[3][3]))));
      #pragma unroll
      for (int msk = 1; msk < 16; msk <<= 1) mx = fmaxf(mx, __shfl_xor(mx, msk));
      if (__any(mx > mB + 8.f)) {
        float mn = fmaxf(mB, mx);
        float corr = EXP2F(mB - mn);
        #pragma unroll
        for (int j = 0; j < 4; j++) lB[j] *= corr;
        #pragma unroll
        for (int cf = 0; cf < 4; cf++)
          #pragma unroll
          for (int j = 0; j < 4; j++) oB[cf][j] *= corr;
        mB = mn;
      }
      #pragma unroll
      for (int cc = 0; cc < 4; cc++)
        #pragma unroll
        for (int j = 0; j < 4; j++) {
          float p = EXP2F(sB[cc][j] - mB);
          lB[j] += p;
          int row = g * 4 + j;
          pool[wave][row][(((cc * 2 + (c15 >> 3)) ^ (row & 7)) << 3) | (c15 & 7)] =
              f2bf(p);
        }
      asm volatile("s_waitcnt lgkmcnt(0)" ::: "memory");
      __builtin_amdgcn_sched_barrier(0);
      s16x8 pa0 = *(const s16x8*)&pool[wave][c15][(g ^ (c15 & 7)) << 3];
      s16x8 pa1 = *(const s16x8*)&pool[wave][c15][((4 + g) ^ (c15 & 7)) << 3];
      __builtin_amdgcn_s_setprio(1);
      #pragma unroll
      for (int cf = 0; cf < 4; cf++) {
        int cv = cf * 16 + c15;
        const u16* vr = &Vs[buf][cv * 64];
        oB[cf] = mfma16(pa0, *(const s16x8*)(vr + ((g ^ (cv & 7)) << 3)), oB[cf]);
        oB[cf] = mfma16(pa1, *(const s16x8*)(vr + (((4 + g) ^ (cv & 7)) << 3)), oB[cf]);
      }
      __builtin_amdgcn_s_setprio(0);
    }
  }
  // epilogue: reduce denominators across 16 key-lanes, normalize, store both tiles
  #pragma unroll
  for (int j = 0; j < 4; j++) {
    #pragma unroll
    for (int msk = 1; msk < 16; msk <<= 1) {
      lA[j] += __shfl_xor(lA[j], msk);
      lB[j] += __shfl_xor(lB[j], msk);
    }
    lA[j] = 1.0f / lA[j];
    lB[j] = 1.0f / lB[j];
  }
  #pragma unroll
  for (int j = 0; j < 4; j++) {
    int tA = tok_of(wi, n0 + g * 4 + j);
    int tB = tok_of(wi, n0 + 16 + g * 4 + j);
    u16* orA = out + (size_t)tA * NDIM + hh * 64;
    u16* orB = out + (size_t)tB * NDIM + hh * 64;
    #pragma unroll
    for (int cf = 0; cf < 4; cf++) {
      orA[cf * 16 + c15] = f2bf(oA[cf][j] * lA[j]);
      orB[cf * 16 + c15] = f2bf(oB[cf][j] * lB[j]);
    }
  }
}

extern "C" void kernel_launch(void* const* d_in, const int* in_sizes, int n_in,
                              void* d_out, int out_size, void* d_ws, size_t ws_size,
                              hipStream_t stream) {
  const float* x     = (const float*)d_in[0];
  const float* ln1_g = (const float*)d_in[1];
  const float* ln1_b = (const float*)d_in[2];
  const float* qkv_w = (const float*)d_in[3];
  const float* qkv_b = (const float*)d_in[4];
  const float* rpd   = (const float*)d_in[5];
  const float* rph   = (const float*)d_in[6];
  const float* rpw   = (const float*)d_in[7];
  const float* proj_w = (const float*)d_in[8];
  const float* proj_b = (const float*)d_in[9];
  const float* aa1_w = (const float*)d_in[10];
  const float* aa1_b = (const float*)d_in[11];
  const float* aa2_w = (const float*)d_in[12];
  const float* aa2_b = (const float*)d_in[13];
  const float* ln2_g = (const float*)d_in[14];
  const float* ln2_b = (const float*)d_in[15];
  const float* mlp1_w = (const float*)d_in[16];
  const float* mlp1_b = (const float*)d_in[17];
  const float* mlp2_w = (const float*)d_in[18];
  const float* mlp2_b = (const float*)d_in[19];
  const float* ma1_w = (const float*)d_in[20];
  const float* ma1_b = (const float*)d_in[21];
  const float* ma2_w = (const float*)d_in[22];
  const float* ma2_b = (const float*)d_in[23];
  float* out = (float*)d_out;
  char* ws = (char*)d_ws;

  // arena (explicit lifetimes; total ~157 MB)
  u16* wqkv  = (u16*)(ws + 0);          // 3538944 B
  u16* wproj = (u16*)(ws + 3538944);    // 1179648
  u16* wmlp1 = (u16*)(ws + 4718592);    // 4718592
  u16* wmlp2 = (u16*)(ws + 9437184);    // 4718592
  u16* waa1  = (u16*)(ws + 14155776);   // 294912
  u16* waa2  = (u16*)(ws + 14450688);   // 294912
  u16* wma1  = (u16*)(ws + 14745600);   // 294912
  u16* wma2  = (u16*)(ws + 15040512);   // 294912 (x0.5 folded)
  u16* h1    = (u16*)(ws + 15335424);   // 12.58 MB: LN1 out, then reused as attn_out
  u16* attno = h1;
  u16* qkvp  = (u16*)(ws + 27918336);   // 37.75 MB: packed Qp|Kp|Vp, later p_bf
  u16* p_bf  = (u16*)(ws + 53084160);
  u16* vtp   = (u16*)(ws + 65667072);   // 12.58 MB: V_t, then hn
  u16* hn    = vtp;
  float* h_f = (float*)(ws + 78249984); // 25.17 MB
  u16* ah    = (u16*)(ws + 103415808);  // adapter hidden, then mlp hidden (50.33 MB)
  u16* mlph  = ah;
  u16* mah   = (u16*)(ws + 153747456);  // 3.15 MB (used after attn)
  // rpbf aliases mah head: written by conv (first), read by attn, dead before ma1
  u16* rpbf  = (u16*)(ws + 153747456);  // 5760 B transient
  (void)ws_size; (void)in_sizes; (void)n_in; (void)out_size;

  u16* Qp = qkvp;
  u16* Kp = qkvp + (size_t)WHN * WHSZ;
  u16* Vp = qkvp + 2 * (size_t)WHN * WHSZ;

  WConv wc;
  for (int i = 0; i < 11; i++) wc.scl[i] = 1.0f;
  wc.src[0] = qkv_w;  wc.dst[0] = wqkv;  wc.n[0] = 2304 * 768;
  wc.src[1] = proj_w; wc.dst[1] = wproj; wc.n[1] = 768 * 768;
  wc.src[2] = mlp1_w; wc.dst[2] = wmlp1; wc.n[2] = 3072 * 768;
  wc.src[3] = mlp2_w; wc.dst[3] = wmlp2; wc.n[3] = 768 * 3072;
  wc.src[4] = aa1_w;  wc.dst[4] = waa1;  wc.n[4] = 192 * 768;
  wc.src[5] = aa2_w;  wc.dst[5] = waa2;  wc.n[5] = 768 * 192;
  wc.src[6] = ma1_w;  wc.dst[6] = wma1;  wc.n[6] = 192 * 768;
  wc.src[7] = ma2_w;  wc.dst[7] = wma2;  wc.n[7] = 768 * 192;
  wc.scl[7] = 0.5f;   // ADAPT_SCALE folded into wma2
  wc.src[8] = rpd;    wc.dst[8] = rpbf;  wc.n[8] = 15 * 64;
  wc.src[9] = rph;    wc.dst[9] = rpbf + 960;  wc.n[9] = 15 * 64;
  wc.src[10] = rpw;   wc.dst[10] = rpbf + 1920; wc.n[10] = 15 * 64;
  conv_weights<<<1024, 256, 0, stream>>>(wc);

  ln_bf16<<<TOK, 256, 0, stream>>>(x, ln1_g, ln1_b, h1);
  // qkv: 64x64 wave tiles (4x2 wave grid), 2 blocks/CU
  gemm_bf16<256, 128, 512, 3, 6><<<dim3(32, 18), 512, 0, stream>>>(
      h1, wqkv, qkv_b, TOK, 2304, 768, qkvp, nullptr, nullptr,
      nullptr, nullptr, 0, nullptr);
  repack_v<<<192, 256, 0, stream>>>(Vp, vtp);
  attn_win<<<768, 256, 0, stream>>>(Qp, Kp, vtp, rpbf, attno);
  // N=768 GEMMs: 512 thr, 32x64 wave tiles, 48KB LDS -> 3 blocks/CU (24 waves)
  gemm_bf16<128, 128, 512, 3, 0><<<dim3(64, 6), 512, 0, stream>>>(
      attno, wproj, proj_b, TOK, 768, 768, p_bf, nullptr, nullptr,
      nullptr, nullptr, 0, nullptr);
  gemm_bf16<64, 64, 256, 3, 2><<<dim3(128, 3), 256, 0, stream>>>(
      p_bf, waa1, aa1_b, TOK, 192, 768, ah, nullptr, nullptr,
      nullptr, nullptr, 0, nullptr);
  gemm_bf16<128, 128, 512, 3, 3><<<dim3(64, 6), 512, 0, stream>>>(
      ah, waa2, aa2_b, TOK, 768, 192, p_bf, h_f, x,
      nullptr, nullptr, 0, nullptr);
  ln_bf16<<<TOK, 256, 0, stream>>>(h_f, ln2_g, ln2_b, hn);
  gemm_bf16<64, 64, 256, 3, 2><<<dim3(128, 3), 256, 0, stream>>>(
      hn, wma1, ma1_b, TOK, 192, 768, mah, nullptr, nullptr,
      nullptr, nullptr, 0, nullptr);
  gemm_bf16<256, 128, 512, 3, 2><<<dim3(32, 24), 512, 0, stream>>>(
      hn, wmlp1, mlp1_b, TOK, 3072, 768, mlph, nullptr, nullptr,
      nullptr, nullptr, 0, nullptr);
  // fused: out = h_f + (mlph@wmlp2^T + b) + 0.5*(mah@wma2^T + b2)  (0.5 in wma2)
  gemm_bf16<128, 128, 512, 3, 7><<<dim3(64, 6), 512, 0, stream>>>(
      mlph, wmlp2, mlp2_b, TOK, 768, 3072, nullptr, out, h_f,
      mah, wma2, 192, ma2_b);
}

// Round 15
// 299.721 us; speedup vs baseline: 1.1764x; 1.0777x over previous
//
#include <hip/hip_runtime.h>

typedef unsigned short u16;
typedef __attribute__((ext_vector_type(4))) float f32x4;
typedef __attribute__((ext_vector_type(8))) short s16x8;

#define TOK 8192
#define NDIM 768
#define NHEADS 12
#define WHN 192            // window-heads
#define WHSZ 32768         // 512*64 elements per window-head plane
#define L2E 1.4426950408889634f
#define SCL2 (0.125f * L2E)

#if __has_builtin(__builtin_amdgcn_exp2f)
#define EXP2F __builtin_amdgcn_exp2f
#else
#define EXP2F exp2f
#endif

__device__ __forceinline__ u16 f2bf(float f) {
  union { float f; unsigned u; } x; x.f = f;
  unsigned r = x.u + 0x7fffu + ((x.u >> 16) & 1u);
  return (u16)(r >> 16);
}
__device__ __forceinline__ float bf2f(u16 u) {
  union { unsigned u; float f; } x; x.u = ((unsigned)u) << 16;
  return x.f;
}
// fast erf-based exact GELU (A&S 7.1.26, |err| <= 1.5e-7)
__device__ __forceinline__ float gelu_f(float v) {
  float z = fabsf(v) * 0.70710678118654752f;
  float t = __builtin_amdgcn_rcpf(1.0f + 0.3275911f * z);
  float poly = t * (0.254829592f +
               t * (-0.284496736f +
               t * (1.421413741f +
               t * (-1.453152027f + t * 1.061405429f))));
  float erfv = 1.0f - poly * __expf(-z * z);
  erfv = copysignf(erfv, v);
  return 0.5f * v * (1.0f + erfv);
}
__device__ __forceinline__ f32x4 mfma16(s16x8 a, s16x8 b, f32x4 c) {
  return __builtin_amdgcn_mfma_f32_16x16x32_bf16(a, b, c, 0, 0, 0);
}
__device__ __forceinline__ void glds16(const u16* g, u16* l) {
  __builtin_amdgcn_global_load_lds(
      (const __attribute__((address_space(1))) unsigned int*)g,
      (__attribute__((address_space(3))) unsigned int*)l, 16, 0, 0);
}
// counted vmcnt wait (literal immediates), with scheduling fence (rule #18)
template<int N> __device__ __forceinline__ void waitvm() {
  if constexpr (N == 0)      asm volatile("s_waitcnt vmcnt(0)" ::: "memory");
  else if constexpr (N == 2) asm volatile("s_waitcnt vmcnt(2)" ::: "memory");
  else if constexpr (N == 3) asm volatile("s_waitcnt vmcnt(3)" ::: "memory");
  else if constexpr (N == 4) asm volatile("s_waitcnt vmcnt(4)" ::: "memory");
  else if constexpr (N == 6) asm volatile("s_waitcnt vmcnt(6)" ::: "memory");
  else if constexpr (N == 8) asm volatile("s_waitcnt vmcnt(8)" ::: "memory");
  else if constexpr (N == 12) asm volatile("s_waitcnt vmcnt(12)" ::: "memory");
  __builtin_amdgcn_sched_barrier(0);
}
// window (wi in [0,16), n in [0,512)) -> flat spatial token index
__device__ __forceinline__ int tok_of(int wi, int n) {
  int b = wi >> 3;
  int d = (((wi >> 2) & 1) << 3) | (n >> 6);
  int h = (((wi >> 1) & 1) << 3) | ((n >> 3) & 7);
  int w = ((wi & 1) << 3) | (n & 7);
  return (b << 12) | (d << 8) | (h << 4) | w;
}

// ------ fp32 -> bf16 conversion (weights + rel-pos tables), optional scale ------
struct WConv {
  const float* src[11];
  u16* dst[11];
  int n[11];
  float scl[11];
};
__global__ __launch_bounds__(256) void conv_weights(WConv a) {
  int stride = gridDim.x * blockDim.x;
  int t0 = blockIdx.x * blockDim.x + threadIdx.x;
  for (int s = 0; s < 11; s++) {
    const float4* src = (const float4*)a.src[s];
    u16* dst = a.dst[s];
    float sc = a.scl[s];
    int n4 = a.n[s] >> 2;
    for (int i = t0; i < n4; i += stride) {
      float4 v = src[i];
      ushort4 o;
      o.x = f2bf(v.x * sc); o.y = f2bf(v.y * sc);
      o.z = f2bf(v.z * sc); o.w = f2bf(v.w * sc);
      *(ushort4*)(dst + 4 * (size_t)i) = o;
    }
  }
}

// ---------------- LayerNorm (fp32 in -> bf16 out) ----------------
__global__ __launch_bounds__(256) void ln_bf16(const float* __restrict__ in,
    const float* __restrict__ gamma, const float* __restrict__ beta,
    u16* __restrict__ out) {
  const int row = blockIdx.x;
  const int tid = threadIdx.x;
  const float* xr = in + (size_t)row * NDIM;
  float v0 = xr[tid], v1 = xr[tid + 256], v2 = xr[tid + 512];
  float s = v0 + v1 + v2;
  float q = v0 * v0 + v1 * v1 + v2 * v2;
  for (int o = 32; o; o >>= 1) { s += __shfl_down(s, o); q += __shfl_down(q, o); }
  __shared__ float ss[4], sq[4];
  int wave = tid >> 6, lane = tid & 63;
  if (lane == 0) { ss[wave] = s; sq[wave] = q; }
  __syncthreads();
  s = ss[0] + ss[1] + ss[2] + ss[3];
  q = sq[0] + sq[1] + sq[2] + sq[3];
  float mean = s * (1.0f / 768.0f);
  float var = q * (1.0f / 768.0f) - mean * mean;
  float rstd = rsqrtf(var + 1e-5f);
  u16* orow = out + (size_t)row * NDIM;
  float v[3] = {v0, v1, v2};
  #pragma unroll
  for (int i = 0; i < 3; i++) {
    int c = tid + i * 256;
    orow[c] = f2bf((v[i] - mean) * rstd * gamma[c] + beta[c]);
  }
}

// ---------------- LayerNorm (bf16 in -> bf16 out) ----------------
__global__ __launch_bounds__(256) void ln_bf16b(const u16* __restrict__ in,
    const float* __restrict__ gamma, const float* __restrict__ beta,
    u16* __restrict__ out) {
  const int row = blockIdx.x;
  const int tid = threadIdx.x;
  const u16* xr = in + (size_t)row * NDIM;
  float v0 = bf2f(xr[tid]), v1 = bf2f(xr[tid + 256]), v2 = bf2f(xr[tid + 512]);
  float s = v0 + v1 + v2;
  float q = v0 * v0 + v1 * v1 + v2 * v2;
  for (int o = 32; o; o >>= 1) { s += __shfl_down(s, o); q += __shfl_down(q, o); }
  __shared__ float ss[4], sq[4];
  int wave = tid >> 6, lane = tid & 63;
  if (lane == 0) { ss[wave] = s; sq[wave] = q; }
  __syncthreads();
  s = ss[0] + ss[1] + ss[2] + ss[3];
  q = sq[0] + sq[1] + sq[2] + sq[3];
  float mean = s * (1.0f / 768.0f);
  float var = q * (1.0f / 768.0f) - mean * mean;
  float rstd = rsqrtf(var + 1e-5f);
  u16* orow = out + (size_t)row * NDIM;
  float v[3] = {v0, v1, v2};
  #pragma unroll
  for (int i = 0; i < 3; i++) {
    int c = tid + i * 256;
    orow[c] = f2bf((v[i] - mean) * rstd * gamma[c] + beta[c]);
  }
}

// ---- GEMM: C[M,N] = A[M,K](bf16) * W[N,K]^T(bf16) + bias ----
// NBUF-buffer rotation, counted vmcnt, 1 raw barrier per K-step.
// Wave grid: TPB=256 -> 2x2 (tile BM/2 x BN/2); TPB=512 -> 2x4 (tile BM/2 x BN/4).
// LDS swizzle (verified conflict-free): store source unit (L&3)^((L>>3)&3)
// at slot L&3; read g^((r>>1)&3). 2 lanes/bank = free.
// EPI 0: bf16 store; 2: gelu->bf16; 3: h_b(bf16)=add1+bf2f(obf)+v;
// EPI 6: packed QKV; EPI 7: dual-K fused, out=bf2f(h_b)+v
template<int BM, int BN, int TPB, int NBUF, int EPI>
__global__ __launch_bounds__(TPB) void gemm_bf16(
    const u16* __restrict__ A, const u16* __restrict__ W,
    const float* __restrict__ bias, int M, int N, int K,
    u16* __restrict__ obf, float* __restrict__ of,
    const float* __restrict__ add1,
    const u16* __restrict__ A2, const u16* __restrict__ W2, int K2,
    const float* __restrict__ bias2) {
  constexpr int BK = 32;
  constexpr int WCOLS = TPB / 128;          // 2 (256thr) or 4 (512thr)
  constexpr int WM = BM / 2, WN = BN / WCOLS;
  constexpr int MF = WM / 16, NF = WN / 16;
  constexpr int ACH = BM * BK / (8 * TPB);  // 16B chunks per thread for A
  constexpr int BCH = BN * BK / (8 * TPB);
  constexpr int LPT = ACH + BCH;            // glds per thread per tile
  __shared__ __align__(16) u16 As[NBUF][BM * BK];
  __shared__ __align__(16) u16 Bs[NBUF][BN * BK];
  const int bm = blockIdx.x, bn = blockIdx.y;
  const int tid = threadIdx.x;
  const int wave = tid >> 6, lane = tid & 63;
  const int wr = wave / WCOLS, wc = wave % WCOLS;
  const int g = lane >> 4, c15 = lane & 15;
  f32x4 acc[MF][NF] = {};
  // stage: linear LDS dest, 8-phase XOR-swizzled global source
  auto stage = [&](const u16* Ab_, const u16* Wb_, int Kst, int k0, int b) {
    #pragma unroll
    for (int i = 0; i < ACH; i++) {
      int L = i * TPB + tid;  // row = L>>2, unit = L&3, swz = u ^ ((row>>1)&3)
      glds16(Ab_ + (size_t)(L >> 2) * Kst + k0 + (((L & 3) ^ ((L >> 3) & 3)) * 8),
             &As[b][L * 8]);
    }
    #pragma unroll
    for (int i = 0; i < BCH; i++) {
      int L = i * TPB + tid;
      glds16(Wb_ + (size_t)(L >> 2) * Kst + k0 + (((L & 3) ^ ((L >> 3) & 3)) * 8),
             &Bs[b][L * 8]);
    }
  };
  // full pipelined pass over one operand pair, accumulating into acc
  auto gloop = [&](const u16* Ap, const u16* Wp, int Kst) {
    const u16* Ab_ = Ap + (size_t)(bm * BM) * Kst;
    const u16* Wb_ = Wp + (size_t)(bn * BN) * Kst;
    const int NT = Kst / BK;
    // entry guard: own LDS reads done + all waves past previous use
    asm volatile("s_waitcnt lgkmcnt(0)" ::: "memory");
    __builtin_amdgcn_s_barrier();
    __builtin_amdgcn_sched_barrier(0);
    for (int p = 0; p < NBUF - 1 && p < NT; p++) stage(Ab_, Wb_, Kst, p * BK, p);
    for (int t = 0; t < NT; t++) {
      int buf = t % NBUF;
      if constexpr (NBUF == 4) {
        if (t + 2 < NT) waitvm<2 * LPT>();
        else if (t + 1 < NT) waitvm<LPT>();
        else waitvm<0>();
      } else {
        if (t + 1 < NT) waitvm<LPT>(); else waitvm<0>();
      }
      __builtin_amdgcn_s_barrier();
      __builtin_amdgcn_sched_barrier(0);
      if (t + NBUF - 1 < NT) stage(Ab_, Wb_, Kst, (t + NBUF - 1) * BK,
                                   (t + NBUF - 1) % NBUF);
      s16x8 af[MF], bfr[NF];
      #pragma unroll
      for (int mi = 0; mi < MF; mi++) {
        int r = wr * WM + mi * 16 + c15;
        af[mi] = *(const s16x8*)&As[buf][r * BK + ((g ^ ((r >> 1) & 3)) << 3)];
      }
      #pragma unroll
      for (int ni = 0; ni < NF; ni++) {
        int r = wc * WN + ni * 16 + c15;
        bfr[ni] = *(const s16x8*)&Bs[buf][r * BK + ((g ^ ((r >> 1) & 3)) << 3)];
      }
      __builtin_amdgcn_s_setprio(1);
      #pragma unroll
      for (int mi = 0; mi < MF; mi++)
        #pragma unroll
        for (int ni = 0; ni < NF; ni++)
          acc[mi][ni] = mfma16(af[mi], bfr[ni], acc[mi][ni]);
      __builtin_amdgcn_s_setprio(0);
    }
  };
  gloop(A, W, K);
  if constexpr (EPI == 7) gloop(A2, W2, K2);
  #pragma unroll
  for (int mi = 0; mi < MF; mi++) {
    #pragma unroll
    for (int ni = 0; ni < NF; ni++) {
      int col = bn * BN + wc * WN + ni * 16 + c15;
      float bv = bias[col];
      if (EPI == 7) bv += 0.5f * bias2[col];
      #pragma unroll
      for (int j = 0; j < 4; j++) {
        int row = bm * BM + wr * WM + mi * 16 + g * 4 + j;
        size_t idx = (size_t)row * N + col;
        float v = acc[mi][ni][j] + bv;
        if (EPI == 0) {
          obf[idx] = f2bf(v);
        } else if (EPI == 2) {
          obf[idx] = f2bf(gelu_f(v));
        } else if (EPI == 3) {
          // h_b (bf16) = x + attn-proj(bf16 readback) + adapter
          ((u16*)of)[idx] = f2bf(add1[idx] + bf2f(obf[idx]) + v);
        } else if (EPI == 7) {
          // out = h_b(bf16) + mlp2 + 0.5*ma2 (0.5 folded into wma2)
          of[idx] = bf2f(((const u16*)add1)[idx]) + v;
        } else if (EPI == 6) {
          // packed QKV: seg 0/1/2 -> Qp/Kp/Vp [whi][n][64]
          int seg = col >= 1536 ? 2 : (col >= 768 ? 1 : 0);
          int cc_ = col - seg * 768;
          int hh = cc_ >> 6, c = cc_ & 63;
          int t2 = row;
          int b = t2 >> 12, d = (t2 >> 8) & 15, hy = (t2 >> 4) & 15, wx = t2 & 15;
          int wi = (b << 3) | ((d >> 3) << 2) | ((hy >> 3) << 1) | (wx >> 3);
          int n = ((d & 7) << 6) | ((hy & 7) << 3) | (wx & 7);
          obf[(size_t)seg * (WHN * WHSZ) +
              ((size_t)(wi * NHEADS + hh) * 512 + n) * 64 + c] = f2bf(v);
        }
      }
    }
  }
}

// ---------------- transpose Vp[whi][n][c] -> Vt[whi][c][n] ----------------
__global__ __launch_bounds__(256) void repack_v(const u16* __restrict__ vp,
                                                u16* __restrict__ vt) {
  int whi = blockIdx.x;
  __shared__ u16 Vs[512 * 64];  // XOR-swizzled: slot(n,c) = n*64 + (c ^ (n&63))
  int tid = threadIdx.x;
  const u16* src = vp + (size_t)whi * WHSZ;
  for (int idx = tid; idx < 512 * 64; idx += 256) {
    int n = idx >> 6, c = idx & 63;
    Vs[(n << 6) | (c ^ (n & 63))] = src[idx];
  }
  __syncthreads();
  size_t base = (size_t)whi * WHSZ;
  #pragma unroll 1
  for (int i = 0; i < 32; i++) {
    int idx4 = tid + i * 256;  // 0..8191
    int c = idx4 >> 7, np = (idx4 & 127) << 2;
    ushort4 o;
    o.x = Vs[((np + 0) << 6) | (c ^ ((np + 0) & 63))];
    o.y = Vs[((np + 1) << 6) | (c ^ ((np + 1) & 63))];
    o.z = Vs[((np + 2) << 6) | (c ^ ((np + 2) & 63))];
    o.w = Vs[((np + 3) << 6) | (c ^ ((np + 3) & 63))];
    *(ushort4*)(vt + base + (size_t)c * 512 + np) = o;
  }
}

// ------- windowed attention: MFMA rel-pos prolog, exp2 softmax, counted-vmcnt ------
// grid: 768 blocks, blk = qblk*192 + whi (same whi -> same XCD L2)
// 4 waves x 32 q-rows (2 tiles of 16); 64-key chunks.
__global__ __launch_bounds__(256) void attn_win(const u16* __restrict__ Qp,
    const u16* __restrict__ Kp, const u16* __restrict__ vt,
    const u16* __restrict__ rpbf, u16* __restrict__ out) {
  int blk = blockIdx.x;
  int whi = blk % WHN, qblk = blk / WHN;
  int wi = whi / NHEADS, hh = whi % NHEADS;
  int tid = threadIdx.x;
  int wave = tid >> 6, lane = tid & 63;
  int g = lane >> 4, c15 = lane & 15;
  int n0 = qblk * 128 + wave * 32;
  __shared__ __align__(16) u16 Ks[2][4096];     // 64 rows x 64 u16, 16B-unit XOR-swizzled
  __shared__ __align__(16) u16 Vs[2][4096];     // 64 c-rows x 64 keys, same swizzle
  __shared__ float relf[4][32][16];             // 8KB: rel_d full table (xL2E)
  __shared__ __align__(16) u16 pool[4][16][64]; // 8KB: P staging (swizzled)
  const u16* qbase = Qp + (size_t)whi * WHSZ;
  const u16* kbase = Kp + (size_t)whi * WHSZ;
  const u16* vbase = vt + (size_t)whi * WHSZ;

  auto stage = [&](int kc, int buf) {
    #pragma unroll
    for (int i = 0; i < 2; i++) {
      int seg = wave * 2048 + i * 1024 + lane * 16;  // byte offset in 8KB buffer
      int r = seg >> 7, u = (seg >> 4) & 7;
      int su = (u ^ (r & 7)) << 3;                   // swizzled unit, u16 offset
      glds16(kbase + (size_t)(kc + r) * 64 + su, &Ks[buf][seg >> 1]);
      glds16(vbase + (size_t)r * 512 + kc + su, &Vs[buf][seg >> 1]);
    }
  };

  stage(0, 0);  // chunk 0 -> buf 0 (touches buffer 0 only)

  // Q A-fragments for the two 16-row tiles
  const u16* qbA = qbase + (size_t)(n0 + c15) * 64;
  const u16* qbB = qbase + (size_t)(n0 + 16 + c15) * 64;
  s16x8 aA0 = *(const s16x8*)(qbA + g * 8);
  s16x8 aA1 = *(const s16x8*)(qbA + 32 + g * 8);
  s16x8 aB0 = *(const s16x8*)(qbB + g * 8);
  s16x8 aB1 = *(const s16x8*)(qbB + 32 + g * 8);

  // rel-pos via MFMA: S_rel[q][t] = Q . RP^T (t = table row 0..14)
  // axis d -> relf (kept all loop); axes h,w -> transient scratch aliasing
  // K/V buffer 1 (not staged until after the first loop barrier -> race-free).
  float* scr = (wave < 2) ? (float*)&Ks[1][0] + wave * 1024
                          : (float*)&Vs[1][0] + (wave - 2) * 1024;
  int c15c = c15 < 14 ? c15 : 14;
  #pragma unroll
  for (int ax = 0; ax < 3; ax++) {
    const u16* tb = rpbf + ax * 960 + c15c * 64;
    s16x8 b0 = *(const s16x8*)(tb + g * 8);
    s16x8 b1 = *(const s16x8*)(tb + 32 + g * 8);
    f32x4 rA = {0.f, 0.f, 0.f, 0.f}, rB = {0.f, 0.f, 0.f, 0.f};
    rA = mfma16(aA0, b0, rA); rA = mfma16(aA1, b1, rA);
    rB = mfma16(aB0, b0, rB); rB = mfma16(aB1, b1, rB);
    #pragma unroll
    for (int j = 0; j < 4; j++) {
      float vA_ = rA[j] * L2E, vB_ = rB[j] * L2E;
      if (ax == 0) {
        relf[wave][g * 4 + j][c15] = vA_;
        relf[wave][16 + g * 4 + j][c15] = vB_;
      } else {
        scr[((ax - 1) * 32 + g * 4 + j) * 16 + c15] = vA_;
        scr[((ax - 1) * 32 + 16 + g * 4 + j) * 16 + c15] = vB_;
      }
    }
  }
  asm volatile("s_waitcnt lgkmcnt(0)" ::: "memory");
  __builtin_amdgcn_sched_barrier(0);

  // hoist rel_h + rel_w into registers; record rel_d column bases
  float rbA[4][4], rbB[4][4];
  int cdA[4], cdB[4];
  #pragma unroll
  for (int j = 0; j < 4; j++) {
    int rAi = g * 4 + j, rBi = 16 + g * 4 + j;
    int nA = n0 + rAi, nB = n0 + rBi;
    cdA[j] = (nA >> 6) + 7;  // in-loop col = cdA[j] - chunk
    cdB[j] = (nB >> 6) + 7;
    int kw = c15 & 7;
    float rwA = scr[(32 + rAi) * 16 + ((nA & 7) - kw + 7)];
    float rwB = scr[(32 + rBi) * 16 + ((nB & 7) - kw + 7)];
    #pragma unroll
    for (int cc = 0; cc < 4; cc++) {
      int kh = (cc * 2 + (c15 >> 3)) & 7;
      rbA[cc][j] = scr[rAi * 16 + (((nA >> 3) & 7) - kh + 7)] + rwA;
      rbB[cc][j] = scr[rBi * 16 + (((nB >> 3) & 7) - kh + 7)] + rwB;
    }
  }

  float mA = -1e30f, mB = -1e30f;   // log2-domain running maxima
  float lA[4] = {0.f, 0.f, 0.f, 0.f}, lB[4] = {0.f, 0.f, 0.f, 0.f};
  f32x4 oA[4] = {}, oB[4] = {};

  for (int c = 0; c < 8; c++) {
    int buf = c & 1;
    waitvm<0>();                      // chunk c landed (issued during compute c-1)
    __builtin_amdgcn_s_barrier();     // also fences scratch-alias before stage(1,..)
    __builtin_amdgcn_sched_barrier(0);
    if (c < 7) stage((c + 1) * 64, buf ^ 1);  // prefetch under compute(c)
    // ---- QK^T both tiles, K fragments loaded once ----
    f32x4 sA[4], sB[4];
    __builtin_amdgcn_s_setprio(1);
    #pragma unroll
    for (int cc = 0; cc < 4; cc++) {
      int r = cc * 16 + c15;
      const u16* kr = &Ks[buf][r * 64];
      s16x8 k0 = *(const s16x8*)(kr + ((g ^ (r & 7)) << 3));
      s16x8 k1 = *(const s16x8*)(kr + (((4 + g) ^ (r & 7)) << 3));
      f32x4 t0 = {0.f, 0.f, 0.f, 0.f};
      t0 = mfma16(aA0, k0, t0);
      sA[cc] = mfma16(aA1, k1, t0);
      f32x4 t1 = {0.f, 0.f, 0.f, 0.f};
      t1 = mfma16(aB0, k0, t1);
      sB[cc] = mfma16(aB1, k1, t1);
    }
    __builtin_amdgcn_s_setprio(0);
    // ---- scale (log2 domain) + rel-pos ----
    float rdA[4], rdB[4];
    #pragma unroll
    for (int j = 0; j < 4; j++) {
      rdA[j] = relf[wave][g * 4 + j][cdA[j] - c];
      rdB[j] = relf[wave][16 + g * 4 + j][cdB[j] - c];
    }
    #pragma unroll
    for (int cc = 0; cc < 4; cc++)
      #pragma unroll
      for (int j = 0; j < 4; j++) {
        sA[cc][j] = sA[cc][j] * SCL2 + (rdA[j] + rbA[cc][j]);
        sB[cc][j] = sB[cc][j] * SCL2 + (rdB[j] + rbB[cc][j]);
      }
    // ================= tile A: softmax + PV =================
    {
      float mx = fmaxf(fmaxf(fmaxf(sA[0][0], sA[0][1]), fmaxf(sA[0][2], sA[0][3])),
                       fmaxf(fmaxf(sA[1][0], sA[1][1]), fmaxf(sA[1][2], sA[1][3])));
      mx = fmaxf(mx, fmaxf(fmaxf(fmaxf(sA[2][0], sA[2][1]), fmaxf(sA[2][2], sA[2][3])),
                           fmaxf(fmaxf(sA[3][0], sA[3][1]), fmaxf(sA[3][2], sA[3][3]))));
      #pragma unroll
      for (int msk = 1; msk < 16; msk <<= 1) mx = fmaxf(mx, __shfl_xor(mx, msk));
      if (__any(mx > mA + 8.f)) {      // defer-max: p bounded by 2^8
        float mn = fmaxf(mA, mx);
        float corr = EXP2F(mA - mn);
        #pragma unroll
        for (int j = 0; j < 4; j++) lA[j] *= corr;
        #pragma unroll
        for (int cf = 0; cf < 4; cf++)
          #pragma unroll
          for (int j = 0; j < 4; j++) oA[cf][j] *= corr;
        mA = mn;
      }
      #pragma unroll
      for (int cc = 0; cc < 4; cc++)
        #pragma unroll
        for (int j = 0; j < 4; j++) {
          float p = EXP2F(sA[cc][j] - mA);
          lA[j] += p;
          int row = g * 4 + j;
          pool[wave][row][(((cc * 2 + (c15 >> 3)) ^ (row & 7)) << 3) | (c15 & 7)] =
              f2bf(p);
        }
      asm volatile("s_waitcnt lgkmcnt(0)" ::: "memory");
      __builtin_amdgcn_sched_barrier(0);
      s16x8 pa0 = *(const s16x8*)&pool[wave][c15][(g ^ (c15 & 7)) << 3];
      s16x8 pa1 = *(const s16x8*)&pool[wave][c15][((4 + g) ^ (c15 & 7)) << 3];
      __builtin_amdgcn_s_setprio(1);
      #pragma unroll
      for (int cf = 0; cf < 4; cf++) {
        int cv = cf * 16 + c15;
        const u16* vr = &Vs[buf][cv * 64];
        oA[cf] = mfma16(pa0, *(const s16x8*)(vr + ((g ^ (cv & 7)) << 3)), oA[cf]);
        oA[cf] = mfma16(pa1, *(const s16x8*)(vr + (((4 + g) ^ (cv & 7)) << 3)), oA[cf]);
      }
      __builtin_amdgcn_s_setprio(0);
    }
    // ================= tile B: softmax + PV =================
    {
      float mx = fmaxf(fmaxf(fmaxf(sB[0][0], sB[0][1]), fmaxf(sB[0][2], sB[0][3])),
                       fmaxf(fmaxf(sB[1][0], sB[1][1]), fmaxf(sB[1][2], sB[1][3])));
      mx = fmaxf(mx, fmaxf(fmaxf(fmaxf(sB[2][0], sB[2][1]), fmaxf(sB[2][2], sB[2][3])),
                           fmaxf(fmaxf(sB[3][0], sB[3][1]), fmaxf(sB[3][2], sB[3][3]))));
      #pragma unroll
      for (int msk = 1; msk < 16; msk <<= 1) mx = fmaxf(mx, __shfl_xor(mx, msk));
      if (__any(mx > mB + 8.f)) {
        float mn = fmaxf(mB, mx);
        float corr = EXP2F(mB - mn);
        #pragma unroll
        for (int j = 0; j < 4; j++) lB[j] *= corr;
        #pragma unroll
        for (int cf = 0; cf < 4; cf++)
          #pragma unroll
          for (int j = 0; j < 4; j++) oB[cf][j] *= corr;
        mB = mn;
      }
      #pragma unroll
      for (int cc = 0; cc < 4; cc++)
        #pragma unroll
        for (int j = 0; j < 4; j++) {
          float p = EXP2F(sB[cc][j] - mB);
          lB[j] += p;
          int row = g * 4 + j;
          pool[wave][row][(((cc * 2 + (c15 >> 3)) ^ (row & 7)) << 3) | (c15 & 7)] =
              f2bf(p);
        }
      asm volatile("s_waitcnt lgkmcnt(0)" ::: "memory");
      __builtin_amdgcn_sched_barrier(0);
      s16x8 pa0 = *(const s16x8*)&pool[wave][c15][(g ^ (c15 & 7)) << 3];
      s16x8 pa1 = *(const s16x8*)&pool[wave][c15][((4 + g) ^ (c15 & 7)) << 3];
      __builtin_amdgcn_s_setprio(1);
      #pragma unroll
      for (int cf = 0; cf < 4; cf++) {
        int cv = cf * 16 + c15;
        const u16* vr = &Vs[buf][cv * 64];
        oB[cf] = mfma16(pa0, *(const s16x8*)(vr + ((g ^ (cv & 7)) << 3)), oB[cf]);
        oB[cf] = mfma16(pa1, *(const s16x8*)(vr + (((4 + g) ^ (cv & 7)) << 3)), oB[cf]);
      }
      __builtin_amdgcn_s_setprio(0);
    }
  }
  // epilogue: reduce denominators across 16 key-lanes, normalize, store both tiles
  #pragma unroll
  for (int j = 0; j < 4; j++) {
    #pragma unroll
    for (int msk = 1; msk < 16; msk <<= 1) {
      lA[j] += __shfl_xor(lA[j], msk);
      lB[j] += __shfl_xor(lB[j], msk);
    }
    lA[j] = 1.0f / lA[j];
    lB[j] = 1.0f / lB[j];
  }
  #pragma unroll
  for (int j = 0; j < 4; j++) {
    int tA = tok_of(wi, n0 + g * 4 + j);
    int tB = tok_of(wi, n0 + 16 + g * 4 + j);
    u16* orA = out + (size_t)tA * NDIM + hh * 64;
    u16* orB = out + (size_t)tB * NDIM + hh * 64;
    #pragma unroll
    for (int cf = 0; cf < 4; cf++) {
      orA[cf * 16 + c15] = f2bf(oA[cf][j] * lA[j]);
      orB[cf * 16 + c15] = f2bf(oB[cf][j] * lB[j]);
    }
  }
}

extern "C" void kernel_launch(void* const* d_in, const int* in_sizes, int n_in,
                              void* d_out, int out_size, void* d_ws, size_t ws_size,
                              hipStream_t stream) {
  const float* x     = (const float*)d_in[0];
  const float* ln1_g = (const float*)d_in[1];
  const float* ln1_b = (const float*)d_in[2];
  const float* qkv_w = (const float*)d_in[3];
  const float* qkv_b = (const float*)d_in[4];
  const float* rpd   = (const float*)d_in[5];
  const float* rph   = (const float*)d_in[6];
  const float* rpw   = (const float*)d_in[7];
  const float* proj_w = (const float*)d_in[8];
  const float* proj_b = (const float*)d_in[9];
  const float* aa1_w = (const float*)d_in[10];
  const float* aa1_b = (const float*)d_in[11];
  const float* aa2_w = (const float*)d_in[12];
  const float* aa2_b = (const float*)d_in[13];
  const float* ln2_g = (const float*)d_in[14];
  const float* ln2_b = (const float*)d_in[15];
  const float* mlp1_w = (const float*)d_in[16];
  const float* mlp1_b = (const float*)d_in[17];
  const float* mlp2_w = (const float*)d_in[18];
  const float* mlp2_b = (const float*)d_in[19];
  const float* ma1_w = (const float*)d_in[20];
  const float* ma1_b = (const float*)d_in[21];
  const float* ma2_w = (const float*)d_in[22];
  const float* ma2_b = (const float*)d_in[23];
  float* out = (float*)d_out;
  char* ws = (char*)d_ws;

  // arena (explicit lifetimes)
  u16* wqkv  = (u16*)(ws + 0);          // 3538944 B
  u16* wproj = (u16*)(ws + 3538944);    // 1179648
  u16* wmlp1 = (u16*)(ws + 4718592);    // 4718592
  u16* wmlp2 = (u16*)(ws + 9437184);    // 4718592
  u16* waa1  = (u16*)(ws + 14155776);   // 294912
  u16* waa2  = (u16*)(ws + 14450688);   // 294912
  u16* wma1  = (u16*)(ws + 14745600);   // 294912
  u16* wma2  = (u16*)(ws + 15040512);   // 294912 (x0.5 folded)
  u16* h1    = (u16*)(ws + 15335424);   // 12.58 MB: LN1 out, then reused as attn_out
  u16* attno = h1;
  u16* qkvp  = (u16*)(ws + 27918336);   // 37.75 MB: packed Qp|Kp|Vp
  u16* p_bf  = (u16*)(ws + 53084160);
  u16* vtp   = (u16*)(ws + 65667072);   // 12.58 MB: V_t, then hn
  u16* hn    = vtp;
  u16* h_b   = (u16*)(ws + 78249984);   // 12.58 MB bf16 residual h
  u16* ah    = (u16*)(ws + 103415808);  // adapter hidden, then mlp hidden (50.33 MB)
  u16* mlph  = ah;
  u16* mah   = (u16*)(ws + 153747456);  // 3.15 MB (used after attn)
  // rpbf aliases mah head: written by conv (first), read by attn, dead before ma1
  u16* rpbf  = (u16*)(ws + 153747456);  // 5760 B transient
  (void)ws_size; (void)in_sizes; (void)n_in; (void)out_size;

  u16* Qp = qkvp;
  u16* Kp = qkvp + (size_t)WHN * WHSZ;
  u16* Vp = qkvp + 2 * (size_t)WHN * WHSZ;

  WConv wc;
  for (int i = 0; i < 11; i++) wc.scl[i] = 1.0f;
  wc.src[0] = qkv_w;  wc.dst[0] = wqkv;  wc.n[0] = 2304 * 768;
  wc.src[1] = proj_w; wc.dst[1] = wproj; wc.n[1] = 768 * 768;
  wc.src[2] = mlp1_w; wc.dst[2] = wmlp1; wc.n[2] = 3072 * 768;
  wc.src[3] = mlp2_w; wc.dst[3] = wmlp2; wc.n[3] = 768 * 3072;
  wc.src[4] = aa1_w;  wc.dst[4] = waa1;  wc.n[4] = 192 * 768;
  wc.src[5] = aa2_w;  wc.dst[5] = waa2;  wc.n[5] = 768 * 192;
  wc.src[6] = ma1_w;  wc.dst[6] = wma1;  wc.n[6] = 192 * 768;
  wc.src[7] = ma2_w;  wc.dst[7] = wma2;  wc.n[7] = 768 * 192;
  wc.scl[7] = 0.5f;   // ADAPT_SCALE folded into wma2
  wc.src[8] = rpd;    wc.dst[8] = rpbf;  wc.n[8] = 15 * 64;
  wc.src[9] = rph;    wc.dst[9] = rpbf + 960;  wc.n[9] = 15 * 64;
  wc.src[10] = rpw;   wc.dst[10] = rpbf + 1920; wc.n[10] = 15 * 64;
  conv_weights<<<1024, 256, 0, stream>>>(wc);

  ln_bf16<<<TOK, 256, 0, stream>>>(x, ln1_g, ln1_b, h1);
  gemm_bf16<128, 128, 512, 3, 6><<<dim3(64, 18), 512, 0, stream>>>(
      h1, wqkv, qkv_b, TOK, 2304, 768, qkvp, nullptr, nullptr,
      nullptr, nullptr, 0, nullptr);
  repack_v<<<192, 256, 0, stream>>>(Vp, vtp);
  attn_win<<<768, 256, 0, stream>>>(Qp, Kp, vtp, rpbf, attno);
  gemm_bf16<128, 64, 256, 4, 0><<<dim3(64, 12), 256, 0, stream>>>(
      attno, wproj, proj_b, TOK, 768, 768, p_bf, nullptr, nullptr,
      nullptr, nullptr, 0, nullptr);
  gemm_bf16<64, 64, 256, 4, 2><<<dim3(128, 3), 256, 0, stream>>>(
      p_bf, waa1, aa1_b, TOK, 192, 768, ah, nullptr, nullptr,
      nullptr, nullptr, 0, nullptr);
  // h_b (bf16) = x + proj(bf16) + adapter
  gemm_bf16<128, 64, 256, 4, 3><<<dim3(64, 12), 256, 0, stream>>>(
      ah, waa2, aa2_b, TOK, 768, 192, p_bf, (float*)h_b, x,
      nullptr, nullptr, 0, nullptr);
  ln_bf16b<<<TOK, 256, 0, stream>>>(h_b, ln2_g, ln2_b, hn);
  gemm_bf16<64, 64, 256, 4, 2><<<dim3(128, 3), 256, 0, stream>>>(
      hn, wma1, ma1_b, TOK, 192, 768, mah, nullptr, nullptr,
      nullptr, nullptr, 0, nullptr);
  gemm_bf16<128, 128, 512, 3, 2><<<dim3(64, 24), 512, 0, stream>>>(
      hn, wmlp1, mlp1_b, TOK, 3072, 768, mlph, nullptr, nullptr,
      nullptr, nullptr, 0, nullptr);
  // fused: out = h_b + (mlph@wmlp2^T + b) + 0.5*(mah@wma2^T + b2)  (0.5 in wma2)
  gemm_bf16<128, 64, 256, 4, 7><<<dim3(64, 12), 256, 0, stream>>>(
      mlph, wmlp2, mlp2_b, TOK, 768, 3072, nullptr, out, (const float*)h_b,
      mah, wma2, 192, ma2_b);
}